// Round 5
// baseline (280.970 us; speedup 1.0000x reference)
//
#include <hip/hip_runtime.h>
#include <hip/hip_bf16.h>

#define HID 1024
#define HEADS 16
#define HEAD 64
#define RELN 63
#define SEQ 512
#define BATCH 16
#define NROWS (SEQ*BATCH)      // 8192
#define MEXT 8320              // 8192 + 63, padded to 65*128
#define NQKV 3072
#define LNEPS 1e-7f
// 1/sqrt(3*64) * log2(e): all attention-score terms pre-scaled into base-2 domain
#define SCALE2 (0.07216878364870323f * 1.4426950408889634f)

typedef __attribute__((ext_vector_type(4))) float  f32x4;
typedef __attribute__((ext_vector_type(8))) short  s16x8;
typedef __attribute__((ext_vector_type(4))) ushort u16x4;

static __device__ __forceinline__ ushort f2bf(float f) {
  union { float f; unsigned u; } v; v.f = f;
  unsigned r = v.u + 0x7fffu + ((v.u >> 16) & 1u);
  return (ushort)(r >> 16);
}
static __device__ __forceinline__ float bf2f(ushort u) {
  union { unsigned u; float f; } v; v.u = ((unsigned)u) << 16;
  return v.f;
}

// ---------------- prep: mask dtype detect + mask01 + bucket idx table + bias concat ------
__global__ void k_prep(const void* mask_raw, const float* bqk, const float* bv,
                       ushort* mask01, int* idx_tab, float* bcat) {
  __shared__ int s_isbool;
  int tid = threadIdx.x;
  if (tid == 0) s_isbool = 0;
  __syncthreads();
  const unsigned* mu = (const unsigned*)mask_raw;
  int bad = 0;
  for (int i = tid; i < 2048; i += 256) if (mu[i] > 1u) bad = 1;
  if (bad) s_isbool = 1;              // benign race: any writer writes 1
  __syncthreads();
  int isbool = s_isbool;
  const unsigned char* m8 = (const unsigned char*)mask_raw;
  const int* m32 = (const int*)mask_raw;
  for (int i = tid; i < BATCH*SEQ; i += 256) {
    int m = isbool ? (int)m8[i] : m32[i];
    mask01[i] = m ? 1 : 0;
  }
  for (int i = tid; i < 1023; i += 256) {
    int r = i - 511;
    int a = r < 0 ? -r : r;
    int absp = (a < 16) ? 15 : (a < 511 ? a : 511);
    int idx;
    if (absp <= 16) idx = 31 + r;
    else {
      float v = logf((float)absp / 16.0f) / logf(511.0f / 16.0f) * 15.0f;
      int lp = (int)ceilf(v) + 16;
      idx = 31 + (r > 0 ? lp : -lp);
    }
    idx_tab[i] = idx;
  }
  for (int i = tid; i < 2048; i += 256) bcat[i] = bqk[i];
  for (int i = tid; i < 1024; i += 256) bcat[2048 + i] = bv[i];
}

// ---------------- f32 -> bf16 weight conversion (wqk|wv concat, wo) ----------------------
__global__ void k_convert(const float* wqk, const float* wv, const float* wo,
                          ushort* wcat, ushort* wo_b) {
  int i = blockIdx.x * 256 + threadIdx.x;
  if (i < 2048 * 1024) wcat[i] = f2bf(wqk[i]);
  else if (i < 3072 * 1024) wcat[i] = f2bf(wv[i - 2048 * 1024]);
  if (i < 1024 * 1024) wo_b[i] = f2bf(wo[i]);
}

// ---------------- LN1 (no affine) -> bf16, plus rel-embedding rows + zero pad ------------
__global__ __launch_bounds__(256) void k_ln1(const float* hid, const float* rel, ushort* h_ext) {
  int row = blockIdx.x, tid = threadIdx.x;
  __shared__ float red[8];
  if (row < NROWS) {
    const float* src = hid + (size_t)row * HID;
    f32x4 x = *(const f32x4*)(src + tid * 4);
    float s = x[0] + x[1] + x[2] + x[3];
    #pragma unroll
    for (int m = 1; m < 64; m <<= 1) s += __shfl_xor(s, m);
    if ((tid & 63) == 0) red[tid >> 6] = s;
    __syncthreads();
    float mean = (red[0] + red[1] + red[2] + red[3]) * (1.0f / HID);
    float d0 = x[0] - mean, d1 = x[1] - mean, d2 = x[2] - mean, d3 = x[3] - mean;
    float sq = d0*d0 + d1*d1 + d2*d2 + d3*d3;
    #pragma unroll
    for (int m = 1; m < 64; m <<= 1) sq += __shfl_xor(sq, m);
    __syncthreads();
    if ((tid & 63) == 0) red[4 + (tid >> 6)] = sq;
    __syncthreads();
    float var = (red[4] + red[5] + red[6] + red[7]) * (1.0f / HID);
    float rs = rsqrtf(var + LNEPS);
    u16x4 o = { f2bf(d0*rs), f2bf(d1*rs), f2bf(d2*rs), f2bf(d3*rs) };
    *(u16x4*)(h_ext + (size_t)row * HID + tid * 4) = o;
  } else if (row < NROWS + RELN) {
    const float* src = rel + (size_t)(row - NROWS) * HID;
    f32x4 x = *(const f32x4*)(src + tid * 4);
    u16x4 o = { f2bf(x[0]), f2bf(x[1]), f2bf(x[2]), f2bf(x[3]) };
    *(u16x4*)(h_ext + (size_t)row * HID + tid * 4) = o;
  } else {
    u16x4 z = { 0, 0, 0, 0 };
    *(u16x4*)(h_ext + (size_t)row * HID + tid * 4) = z;
  }
}

// ---------------- NT GEMM: C[M,N] = A[M,K] * B[N,K]^T + bias, bf16 in, bf16/f32 out ------
// 128x128 tile, BK=64, global_load_lds(16B) with XOR-swizzled global source.
// 1D grid + XCD-chunked block swizzle (grid % 8 == 0).
template<int WRITE_F32>
__global__ __launch_bounds__(256) void k_gemm(const ushort* A, const ushort* Bw, const float* bias,
                                              ushort* Cb, float* Cf, int M, int N, int K) {
  __shared__ char smem[32768];
  char* As = smem;
  char* Bs = smem + 16384;
  int tid = threadIdx.x, lane = tid & 63, w = tid >> 6;
  int nbn = N >> 7;
  int per = gridDim.x >> 3;
  int gl = (blockIdx.x & 7) * per + (blockIdx.x >> 3);
  int bm = gl / nbn, bn = gl % nbn;
  int wr = w >> 1, wc = w & 1;
  int g = lane >> 4, r = lane & 15;
  f32x4 acc[4][4] = {};
  for (int ko = 0; ko < K; ko += 64) {
    __syncthreads();
    #pragma unroll
    for (int c = 0; c < 4; ++c) {
      int chunk = c * 256 + tid;
      int row = chunk >> 3;
      int kb = (chunk & 7) << 4;
      int kbs = kb ^ ((row & 7) << 4);   // pre-swizzled source column (bytes)
      const char* gA = (const char*)(A + (size_t)(bm * 128 + row) * K + ko) + kbs;
      const char* gB = (const char*)(Bw + (size_t)(bn * 128 + row) * K + ko) + kbs;
      __builtin_amdgcn_global_load_lds((const __attribute__((address_space(1))) void*)gA,
                                       (__attribute__((address_space(3))) void*)(As + c * 4096 + w * 1024),
                                       16, 0, 0);
      __builtin_amdgcn_global_load_lds((const __attribute__((address_space(1))) void*)gB,
                                       (__attribute__((address_space(3))) void*)(Bs + c * 4096 + w * 1024),
                                       16, 0, 0);
    }
    __syncthreads();
    #pragma unroll
    for (int kk = 0; kk < 2; ++kk) {
      s16x8 af[4], bf[4];
      #pragma unroll
      for (int mt = 0; mt < 4; ++mt) {
        int row = wr * 64 + mt * 16 + r;
        int kb = (kk * 64 + g * 16) ^ ((row & 7) << 4);
        af[mt] = *(const s16x8*)(As + row * 128 + kb);
      }
      #pragma unroll
      for (int nt = 0; nt < 4; ++nt) {
        int row = wc * 64 + nt * 16 + r;
        int kb = (kk * 64 + g * 16) ^ ((row & 7) << 4);
        bf[nt] = *(const s16x8*)(Bs + row * 128 + kb);
      }
      #pragma unroll
      for (int mt = 0; mt < 4; ++mt)
        #pragma unroll
        for (int nt = 0; nt < 4; ++nt)
          acc[mt][nt] = __builtin_amdgcn_mfma_f32_16x16x32_bf16(af[mt], bf[nt], acc[mt][nt], 0, 0, 0);
    }
  }
  #pragma unroll
  for (int nt = 0; nt < 4; ++nt) {
    int col = bn * 128 + wc * 64 + nt * 16 + r;
    float bvv = bias[col];
    #pragma unroll
    for (int mt = 0; mt < 4; ++mt) {
      int row0 = bm * 128 + wr * 64 + mt * 16 + g * 4;
      #pragma unroll
      for (int i = 0; i < 4; ++i) {
        float v = acc[mt][nt][i] + bvv;
        if (WRITE_F32) Cf[(size_t)(row0 + i) * N + col] = v;
        else           Cb[(size_t)(row0 + i) * N + col] = f2bf(v);
      }
    }
  }
}

// ---------------- positional score tables (bf16, base-2 pre-scaled, mask baked into pk) --
__global__ __launch_bounds__(256) void k_pos(const ushort* qkv, const ushort* mask01,
                                             ushort* qp, ushort* pk) {
  int bh = blockIdx.x;
  int b = bh >> 4, h = bh & 15;
  int tid = threadIdx.x, lane = tid & 63, w = tid >> 6;
  int g = lane >> 4, r = lane & 15;
  __shared__ ushort mb[512];
  for (int i = tid; i < 512; i += 256) mb[i] = mask01[b * SEQ + i];
  __syncthreads();
  s16x8 bkp[4][2], bqp[4][2];   // kpos / qpos B-fragments (t = nt*16+r)
  #pragma unroll
  for (int nt = 0; nt < 4; ++nt)
    #pragma unroll
    for (int kk = 0; kk < 2; ++kk) {
      size_t rowp = (size_t)(NROWS + nt * 16 + r);
      int colq = h * 64 + kk * 32 + g * 8;
      bqp[nt][kk] = *(const s16x8*)(qkv + rowp * NQKV + colq);
      bkp[nt][kk] = *(const s16x8*)(qkv + rowp * NQKV + 1024 + colq);
    }
  for (int cc = 0; cc < 8; ++cc) {
    int rowbase = cc * 64 + w * 16;
    s16x8 aq[2], ak[2];
    #pragma unroll
    for (int kk = 0; kk < 2; ++kk) {
      size_t rowq = (size_t)((rowbase + r) * 16 + b);
      int colq = h * 64 + kk * 32 + g * 8;
      aq[kk] = *(const s16x8*)(qkv + rowq * NQKV + colq);
      ak[kk] = *(const s16x8*)(qkv + rowq * NQKV + 1024 + colq);
    }
    f32x4 accq[4] = {}, acck[4] = {};
    #pragma unroll
    for (int kk = 0; kk < 2; ++kk)
      #pragma unroll
      for (int nt = 0; nt < 4; ++nt) {
        accq[nt] = __builtin_amdgcn_mfma_f32_16x16x32_bf16(aq[kk], bkp[nt][kk], accq[nt], 0, 0, 0);
        acck[nt] = __builtin_amdgcn_mfma_f32_16x16x32_bf16(ak[kk], bqp[nt][kk], acck[nt], 0, 0, 0);
      }
    #pragma unroll
    for (int nt = 0; nt < 4; ++nt)
      #pragma unroll
      for (int i = 0; i < 4; ++i) {
        int q = rowbase + g * 4 + i;
        int t = nt * 16 + r;
        float biasv = mb[q] ? -1e9f : 0.0f;          // mask baked into pk rows
        qp[(size_t)bh * SEQ * 64 + q * 64 + t] = f2bf(accq[nt][i] * SCALE2);
        pk[(size_t)bh * SEQ * 64 + q * 64 + t] = f2bf(acck[nt][i] * SCALE2 + biasv);
      }
  }
}

// ---------------- V transpose + K repack (K pre-scaled, base-2): vt[b,h,d,l], kc[b,h,l,d]
__global__ __launch_bounds__(256) void k_vt(const ushort* qkv, ushort* vt, ushort* kc) {
  int bid = blockIdx.x;
  int bh = bid >> 3, lt = bid & 7;
  int b = bh >> 4, h = bh & 15;
  __shared__ ushort tile[64][72];
  int tid = threadIdx.x;
  #pragma unroll
  for (int c = 0; c < 2; ++c) {
    int e = (c * 256 + tid) * 8;
    int l = e >> 6, d0 = e & 63;
    size_t row = (size_t)((lt * 64 + l) * 16 + b);
    s16x8 kv = *(const s16x8*)(qkv + row * NQKV + 1024 + h * 64 + d0);
    #pragma unroll
    for (int j = 0; j < 8; ++j) kv[j] = (short)f2bf(bf2f((ushort)kv[j]) * SCALE2);
    *(s16x8*)(kc + ((size_t)bh * SEQ + lt * 64 + l) * 64 + d0) = kv;   // scaled K rows
    *(s16x8*)&tile[l][d0] = *(const s16x8*)(qkv + row * NQKV + 2048 + h * 64 + d0);
  }
  __syncthreads();
  #pragma unroll
  for (int c = 0; c < 2; ++c) {
    int e = (c * 256 + tid) * 8;
    int d = e >> 6, l0 = e & 63;
    ushort tmp[8];
    #pragma unroll
    for (int j = 0; j < 8; ++j) tmp[j] = tile[l0 + j][d];
    *(s16x8*)(vt + (size_t)(bh * 64 + d) * SEQ + lt * 64 + l0) = *(s16x8*)tmp;
  }
}

// ---------------- fused attention: SWAPPED QK^T (S^T layout) ------------------------------
// mfma(K,Q) puts a full softmax row per lane (q=lane&15): one (m,l) state/thread,
// local-16 + 2-shfl reductions, b64 P-writes, exp2 domain, T13 defer-rescale.
__global__ __launch_bounds__(256) void k_attn(const ushort* qkv, const ushort* qp_all, const ushort* pk_all,
                                              const ushort* kc, const ushort* vt,
                                              const int* idx_tab, ushort* ctx) {
  int bid = blockIdx.x;
  int slot = bid >> 3;
  int bh = (bid & 7) * 32 + (slot >> 3);   // all 8 qt-blocks of a bh on one XCD
  int qt = slot & 7;
  int b = bh >> 4, h = bh & 15;
  int tid = threadIdx.x, lane = tid & 63, w = tid >> 6;
  int g = lane >> 4, r = lane & 15;

  __shared__ char   Ks[8192];
  __shared__ ushort qp_s[64][72];
  __shared__ ushort pk_s[64][72];
  __shared__ ushort p_s[4][16][72];
  __shared__ unsigned char idx_s[1024];

  const size_t qp_base = (size_t)bh * SEQ * 64 + (size_t)qt * 4096;
  const size_t pk_base = (size_t)bh * SEQ * 64;
  const char* kcb = (const char*)(kc + (size_t)bh * SEQ * 64);   // [l][d] 128B rows

  int krow = w * 8 + (lane >> 3);                   // staging row (+c*32)
  int ksrccol = ((lane & 7) ^ (lane >> 3)) << 4;    // pre-swizzled source col (bytes)

  // ---- prologue: stage K(0), pk(0)->regs->LDS, qp->LDS, idx, aq ----
  #pragma unroll
  for (int c = 0; c < 2; ++c) {
    const char* src = kcb + (size_t)(c * 32 + krow) * 128 + ksrccol;
    __builtin_amdgcn_global_load_lds((const __attribute__((address_space(1))) void*)src,
                                     (__attribute__((address_space(3))) void*)(Ks + c * 4096 + w * 1024),
                                     16, 0, 0);
  }
  s16x8 pkreg[2];
  #pragma unroll
  for (int c = 0; c < 2; ++c)
    pkreg[c] = *(const s16x8*)(pk_all + pk_base + (size_t)(c * 256 + tid) * 8);
  #pragma unroll
  for (int c = 0; c < 2; ++c) {
    int chunk = c * 256 + tid;
    s16x8 v = *(const s16x8*)(qp_all + qp_base + (size_t)chunk * 8);
    *(s16x8*)&qp_s[chunk >> 3][(chunk & 7) * 8] = v;
  }
  for (int i = tid; i < 1023; i += 256) idx_s[i] = (unsigned char)idx_tab[i];
  s16x8 aq[2];
  int qg0 = qt * 64 + w * 16;
  #pragma unroll
  for (int kk = 0; kk < 2; ++kk) {
    size_t row = (size_t)((qg0 + r) * 16 + b);
    aq[kk] = *(const s16x8*)(qkv + row * NQKV + h * 64 + kk * 32 + g * 8);
  }
  #pragma unroll
  for (int c = 0; c < 2; ++c) {
    int chunk = c * 256 + tid;
    *(s16x8*)&pk_s[chunk >> 3][(chunk & 7) * 8] = pkreg[c];
  }
  __syncthreads();   // drains K(0) staging too

  float m_i = -3e38f, l_i = 0.0f;
  f32x4 o_acc[4] = {};
  const ushort* qprow = &qp_s[w * 16 + r][0];      // this thread's q-row (q = w*16+r local)
  const int qglob511 = qt * 64 + w * 16 + r + 511;

  for (int kt = 0; kt < 8; ++kt) {
    // prefetch pk(kt+1) into regs (consumed after barrier A)
    if (kt < 7) {
      #pragma unroll
      for (int c = 0; c < 2; ++c)
        pkreg[c] = *(const s16x8*)(pk_all + pk_base + (size_t)(kt + 1) * 4096 + (size_t)(c * 256 + tid) * 8);
    }

    // ---- swapped QK^T: sT[nt] holds S^T[k_local = g*4+i][q = r] ----
    f32x4 s[4];
    #pragma unroll
    for (int nt = 0; nt < 4; ++nt) {
      f32x4 a = {};
      #pragma unroll
      for (int kk = 0; kk < 2; ++kk) {
        s16x8 bk = *(const s16x8*)(Ks + (nt * 16 + r) * 128 + ((kk * 64 + g * 16) ^ ((r & 7) << 4)));
        a = __builtin_amdgcn_mfma_f32_16x16x32_bf16(bk, aq[kk], a, 0, 0, 0);   // A=K, B=Q
      }
      s[nt] = a;
    }

    // ---- gather pass: v = c2c + qp[q][t] + pk[k][t]  (all base-2 pre-scaled) ----
    float m_loc = -3e38f;
    #pragma unroll
    for (int nt = 0; nt < 4; ++nt) {
      #pragma unroll
      for (int i = 0; i < 4; ++i) {
        int kl = nt * 16 + g * 4 + i;
        int t = idx_s[qglob511 - kt * 64 - kl];
        float v = s[nt][i] + bf2f(qprow[t]) + bf2f(pk_s[kl][t]);
        s[nt][i] = v;
        m_loc = fmaxf(m_loc, v);
      }
    }
    __syncthreads();   // A: all waves done reading Ks + pk_s

    // ---- issue next-tile staging; softmax/PV below covers the latency ----
    if (kt < 7) {
      #pragma unroll
      for (int c = 0; c < 2; ++c) {
        const char* src = kcb + (size_t)(kt + 1) * 8192 + (size_t)(c * 32 + krow) * 128 + ksrccol;
        __builtin_amdgcn_global_load_lds((const __attribute__((address_space(1))) void*)src,
                                         (__attribute__((address_space(3))) void*)(Ks + c * 4096 + w * 1024),
                                         16, 0, 0);
      }
      #pragma unroll
      for (int c = 0; c < 2; ++c) {
        int chunk = c * 256 + tid;
        *(s16x8*)&pk_s[chunk >> 3][(chunk & 7) * 8] = pkreg[c];
      }
    }
    // V loads for this tile
    s16x8 vreg[2][4];
    #pragma unroll
    for (int kk = 0; kk < 2; ++kk)
      #pragma unroll
      for (int nt = 0; nt < 4; ++nt)
        vreg[kk][nt] = *(const s16x8*)(vt + (size_t)(bh * 64 + nt * 16 + r) * SEQ + kt * 64 + kk * 32 + g * 8);

    // ---- row max: local 16 + 2 shfl hops (across g lanes only) ----
    float mx = fmaxf(m_loc, __shfl_xor(m_loc, 16));
    mx = fmaxf(mx, __shfl_xor(mx, 32));

    // ---- T13 defer-rescale: only rescale when max grew by > 8 (base-2) ----
    if (__any(mx > m_i + 8.0f)) {
      float mnew = fmaxf(m_i, mx);
      float rs = exp2f(m_i - mnew);
      m_i = mnew;
      l_i *= rs;
      float rsb[4];
      #pragma unroll
      for (int i = 0; i < 4; ++i) rsb[i] = __shfl(rs, g * 4 + i);   // rs for q=g*4+i
      #pragma unroll
      for (int nt = 0; nt < 4; ++nt)
        #pragma unroll
        for (int i = 0; i < 4; ++i) o_acc[nt][i] *= rsb[i];
    }

    // ---- exp2 + P pack (4 x b64 LDS writes), psum ----
    float psum = 0.0f;
    #pragma unroll
    for (int nt = 0; nt < 4; ++nt) {
      u16x4 pk4;
      #pragma unroll
      for (int i = 0; i < 4; ++i) {
        float pe = exp2f(s[nt][i] - m_i);   // masked: huge negative -> exact 0
        psum += pe;
        pk4[i] = f2bf(pe);
      }
      *(u16x4*)&p_s[w][r][nt * 16 + g * 4] = pk4;
    }
    psum += __shfl_xor(psum, 16);
    psum += __shfl_xor(psum, 32);
    l_i += psum;

    // ---- PV ----
    #pragma unroll
    for (int kk = 0; kk < 2; ++kk) {
      s16x8 pa = *(const s16x8*)&p_s[w][r][kk * 32 + g * 8];
      #pragma unroll
      for (int nt = 0; nt < 4; ++nt)
        o_acc[nt] = __builtin_amdgcn_mfma_f32_16x16x32_bf16(pa, vreg[kk][nt], o_acc[nt], 0, 0, 0);
    }

    if (kt < 7) __syncthreads();   // B: staging + pk_s(kt+1) visible (vmcnt drain overlapped)
  }

  float lb[4];
  #pragma unroll
  for (int i = 0; i < 4; ++i) lb[i] = __shfl(l_i, g * 4 + i);   // l for q=g*4+i
  #pragma unroll
  for (int i = 0; i < 4; ++i) {
    float inv = lb[i] > 0.0f ? 1.0f / lb[i] : 0.0f;
    int lq = qt * 64 + w * 16 + g * 4 + i;
    size_t rowc = (size_t)(lq * 16 + b);
    #pragma unroll
    for (int nt = 0; nt < 4; ++nt)
      ctx[rowc * HID + h * 64 + nt * 16 + r] = f2bf(o_acc[nt][i] * inv);
  }
}

// ---------------- LN2 (affine), bf16 in -> f32 out ---------------------------------------
__global__ __launch_bounds__(256) void k_ln2(const ushort* tmpb, const float* gamma, const float* beta,
                                             float* out) {
  int row = blockIdx.x, tid = threadIdx.x;
  __shared__ float red[8];
  u16x4 xb = *(const u16x4*)(tmpb + (size_t)row * HID + tid * 4);
  float x[4] = { bf2f(xb[0]), bf2f(xb[1]), bf2f(xb[2]), bf2f(xb[3]) };
  float s = x[0] + x[1] + x[2] + x[3];
  #pragma unroll
  for (int m = 1; m < 64; m <<= 1) s += __shfl_xor(s, m);
  if ((tid & 63) == 0) red[tid >> 6] = s;
  __syncthreads();
  float mean = (red[0] + red[1] + red[2] + red[3]) * (1.0f / HID);
  float d[4]; float sq = 0.0f;
  #pragma unroll
  for (int j = 0; j < 4; ++j) { d[j] = x[j] - mean; sq += d[j] * d[j]; }
  #pragma unroll
  for (int m = 1; m < 64; m <<= 1) sq += __shfl_xor(sq, m);
  __syncthreads();
  if ((tid & 63) == 0) red[4 + (tid >> 6)] = sq;
  __syncthreads();
  float var = (red[4] + red[5] + red[6] + red[7]) * (1.0f / HID);
  float rs = rsqrtf(var + LNEPS);
  f32x4 o;
  #pragma unroll
  for (int j = 0; j < 4; ++j) o[j] = d[j] * rs * gamma[tid * 4 + j] + beta[tid * 4 + j];
  *(f32x4*)(out + (size_t)row * HID + tid * 4) = o;
}

// ---------------- launch -----------------------------------------------------------------
extern "C" void kernel_launch(void* const* d_in, const int* in_sizes, int n_in,
                              void* d_out, int out_size, void* d_ws, size_t ws_size,
                              hipStream_t stream) {
  (void)in_sizes; (void)n_in; (void)out_size; (void)ws_size;
  const float* hid  = (const float*)d_in[0];
  const void*  mask = d_in[1];
  const float* rel  = (const float*)d_in[2];
  const float* wqk  = (const float*)d_in[3];
  const float* bqk  = (const float*)d_in[4];
  const float* wv   = (const float*)d_in[5];
  const float* bv   = (const float*)d_in[6];
  const float* wo   = (const float*)d_in[7];
  const float* bo   = (const float*)d_in[8];
  const float* ln_g = (const float*)d_in[9];
  const float* ln_b = (const float*)d_in[10];

  char* ws = (char*)d_ws;
  ushort* wcat     = (ushort*)(ws);                 //  6,291,456
  ushort* wo_b     = (ushort*)(ws + 6291456);       //  2,097,152
  float*  bcat     = (float*) (ws + 8388608);       //     12,288
  ushort* mask01   = (ushort*)(ws + 8400896);       //     16,384 (region 32,768)
  int*    idx_tab  = (int*)   (ws + 8433664);       //      4,096
  ushort* h_ext    = (ushort*)(ws + 8437760);       // 17,039,360  (reused as ctx)
  ushort* qkv      = (ushort*)(ws + 25477120);      // 51,118,080
  ushort* qp_b     = (ushort*)(ws + 76595200);      // 16,777,216 (bf16, base-2 pre-scaled)
  ushort* pk_b     = (ushort*)(ws + 93372416);      // 16,777,216 (bf16, pre-scaled + mask)
  ushort* vt       = (ushort*)(ws + 110149632);     // 16,777,216
  char*   tmpr     = (ws + 126926848);              // 33,554,432 region
  ushort* ctx = h_ext;
  ushort* kc   = (ushort*)tmpr;   // kc[bh][l][d] (scaled) — dead once gemm<1> runs
  ushort* tmpb = (ushort*)tmpr;   // gemm<1> bf16 output overwrites kc (sequential)

  k_prep<<<1, 256, 0, stream>>>(mask, bqk, bv, mask01, idx_tab, bcat);
  k_convert<<<12288, 256, 0, stream>>>(wqk, wv, wo, wcat, wo_b);
  k_ln1<<<MEXT, 256, 0, stream>>>(hid, rel, h_ext);
  k_gemm<0><<<(MEXT / 128) * (NQKV / 128), 256, 0, stream>>>(h_ext, wcat, bcat, qkv, nullptr, MEXT, NQKV, 1024);
  k_pos<<<256, 256, 0, stream>>>(qkv, mask01, qp_b, pk_b);
  k_vt<<<2048, 256, 0, stream>>>(qkv, vt, kc);
  k_attn<<<2048, 256, 0, stream>>>(qkv, qp_b, pk_b, kc, vt, idx_tab, ctx);
  k_gemm<0><<<(NROWS / 128) * (1024 / 128), 256, 0, stream>>>(ctx, wo_b, bo, tmpb, nullptr, NROWS, 1024, 1024);
  k_ln2<<<NROWS, 256, 0, stream>>>(tmpb, ln_g, ln_b, (float*)d_out);
}

// Round 7
// 265.323 us; speedup vs baseline: 1.0590x; 1.0590x over previous
//
#include <hip/hip_runtime.h>
#include <hip/hip_bf16.h>

#define HID 1024
#define HEADS 16
#define HEAD 64
#define RELN 63
#define SEQ 512
#define BATCH 16
#define NROWS (SEQ*BATCH)      // 8192
#define MEXT 8320              // 8192 + 63, padded to 65*128
#define NQKV 3072
#define LNEPS 1e-7f
// 1/sqrt(3*64) * log2(e): all attention-score terms pre-scaled into base-2 domain
#define SCALE2 (0.07216878364870323f * 1.4426950408889634f)

typedef __attribute__((ext_vector_type(4))) float  f32x4;
typedef __attribute__((ext_vector_type(8))) short  s16x8;
typedef __attribute__((ext_vector_type(4))) ushort u16x4;

static __device__ __forceinline__ ushort f2bf(float f) {
  union { float f; unsigned u; } v; v.f = f;
  unsigned r = v.u + 0x7fffu + ((v.u >> 16) & 1u);
  return (ushort)(r >> 16);
}
static __device__ __forceinline__ float bf2f(ushort u) {
  union { unsigned u; float f; } v; v.u = ((unsigned)u) << 16;
  return v.f;
}

// ---------------- prep: mask dtype detect + mask01 + bucket idx table + bias concat ------
__global__ void k_prep(const void* mask_raw, const float* bqk, const float* bv,
                       ushort* mask01, int* idx_tab, float* bcat) {
  __shared__ int s_isbool;
  int tid = threadIdx.x;
  if (tid == 0) s_isbool = 0;
  __syncthreads();
  const unsigned* mu = (const unsigned*)mask_raw;
  int bad = 0;
  for (int i = tid; i < 2048; i += 256) if (mu[i] > 1u) bad = 1;
  if (bad) s_isbool = 1;              // benign race: any writer writes 1
  __syncthreads();
  int isbool = s_isbool;
  const unsigned char* m8 = (const unsigned char*)mask_raw;
  const int* m32 = (const int*)mask_raw;
  for (int i = tid; i < BATCH*SEQ; i += 256) {
    int m = isbool ? (int)m8[i] : m32[i];
    mask01[i] = m ? 1 : 0;
  }
  for (int i = tid; i < 1023; i += 256) {
    int r = i - 511;
    int a = r < 0 ? -r : r;
    int absp = (a < 16) ? 15 : (a < 511 ? a : 511);
    int idx;
    if (absp <= 16) idx = 31 + r;
    else {
      float v = logf((float)absp / 16.0f) / logf(511.0f / 16.0f) * 15.0f;
      int lp = (int)ceilf(v) + 16;
      idx = 31 + (r > 0 ? lp : -lp);
    }
    idx_tab[i] = idx;
  }
  for (int i = tid; i < 2048; i += 256) bcat[i] = bqk[i];
  for (int i = tid; i < 1024; i += 256) bcat[2048 + i] = bv[i];
}

// ---------------- f32 -> bf16 weight conversion, vectorized x4 ---------------------------
__global__ __launch_bounds__(256) void k_convert(const float* wqk, const float* wv, const float* wo,
                                                 ushort* wcat, ushort* wo_b) {
  int c = blockIdx.x * 256 + threadIdx.x;    // 1,048,576 chunks of 4 elems
  f32x4 x; ushort* dst;
  if (c < 524288)      { x = *(const f32x4*)(wqk + (size_t)c * 4);            dst = wcat + (size_t)c * 4; }
  else if (c < 786432) { x = *(const f32x4*)(wv  + (size_t)(c - 524288) * 4); dst = wcat + (size_t)c * 4; }
  else                 { x = *(const f32x4*)(wo  + (size_t)(c - 786432) * 4); dst = wo_b + (size_t)(c - 786432) * 4; }
  u16x4 o = { f2bf(x[0]), f2bf(x[1]), f2bf(x[2]), f2bf(x[3]) };
  *(u16x4*)dst = o;
}

// ---------------- LN1 (no affine) -> bf16, plus rel-embedding rows + zero pad ------------
__global__ __launch_bounds__(256) void k_ln1(const float* hid, const float* rel, ushort* h_ext) {
  int row = blockIdx.x, tid = threadIdx.x;
  __shared__ float red[8];
  if (row < NROWS) {
    const float* src = hid + (size_t)row * HID;
    f32x4 x = *(const f32x4*)(src + tid * 4);
    float s = x[0] + x[1] + x[2] + x[3];
    #pragma unroll
    for (int m = 1; m < 64; m <<= 1) s += __shfl_xor(s, m);
    if ((tid & 63) == 0) red[tid >> 6] = s;
    __syncthreads();
    float mean = (red[0] + red[1] + red[2] + red[3]) * (1.0f / HID);
    float d0 = x[0] - mean, d1 = x[1] - mean, d2 = x[2] - mean, d3 = x[3] - mean;
    float sq = d0*d0 + d1*d1 + d2*d2 + d3*d3;
    #pragma unroll
    for (int m = 1; m < 64; m <<= 1) sq += __shfl_xor(sq, m);
    __syncthreads();
    if ((tid & 63) == 0) red[4 + (tid >> 6)] = sq;
    __syncthreads();
    float var = (red[4] + red[5] + red[6] + red[7]) * (1.0f / HID);
    float rs = rsqrtf(var + LNEPS);
    u16x4 o = { f2bf(d0*rs), f2bf(d1*rs), f2bf(d2*rs), f2bf(d3*rs) };
    *(u16x4*)(h_ext + (size_t)row * HID + tid * 4) = o;
  } else if (row < NROWS + RELN) {
    const float* src = rel + (size_t)(row - NROWS) * HID;
    f32x4 x = *(const f32x4*)(src + tid * 4);
    u16x4 o = { f2bf(x[0]), f2bf(x[1]), f2bf(x[2]), f2bf(x[3]) };
    *(u16x4*)(h_ext + (size_t)row * HID + tid * 4) = o;
  } else {
    u16x4 z = { 0, 0, 0, 0 };
    *(u16x4*)(h_ext + (size_t)row * HID + tid * 4) = z;
  }
}

// ---------------- NT GEMM: C[M,N] = A[M,K] * B[N,K]^T + bias, bf16 in, bf16/f32 out ------
template<int WRITE_F32>
__global__ __launch_bounds__(256) void k_gemm(const ushort* A, const ushort* Bw, const float* bias,
                                              ushort* Cb, float* Cf, int M, int N, int K) {
  __shared__ char smem[32768];
  char* As = smem;
  char* Bs = smem + 16384;
  int tid = threadIdx.x, lane = tid & 63, w = tid >> 6;
  int nbn = N >> 7;
  int per = gridDim.x >> 3;
  int gl = (blockIdx.x & 7) * per + (blockIdx.x >> 3);
  int bm = gl / nbn, bn = gl % nbn;
  int wr = w >> 1, wc = w & 1;
  int g = lane >> 4, r = lane & 15;
  f32x4 acc[4][4] = {};
  for (int ko = 0; ko < K; ko += 64) {
    __syncthreads();
    #pragma unroll
    for (int c = 0; c < 4; ++c) {
      int chunk = c * 256 + tid;
      int row = chunk >> 3;
      int kb = (chunk & 7) << 4;
      int kbs = kb ^ ((row & 7) << 4);   // pre-swizzled source column (bytes)
      const char* gA = (const char*)(A + (size_t)(bm * 128 + row) * K + ko) + kbs;
      const char* gB = (const char*)(Bw + (size_t)(bn * 128 + row) * K + ko) + kbs;
      __builtin_amdgcn_global_load_lds((const __attribute__((address_space(1))) void*)gA,
                                       (__attribute__((address_space(3))) void*)(As + c * 4096 + w * 1024),
                                       16, 0, 0);
      __builtin_amdgcn_global_load_lds((const __attribute__((address_space(1))) void*)gB,
                                       (__attribute__((address_space(3))) void*)(Bs + c * 4096 + w * 1024),
                                       16, 0, 0);
    }
    __syncthreads();
    #pragma unroll
    for (int kk = 0; kk < 2; ++kk) {
      s16x8 af[4], bf[4];
      #pragma unroll
      for (int mt = 0; mt < 4; ++mt) {
        int row = wr * 64 + mt * 16 + r;
        int kb = (kk * 64 + g * 16) ^ ((row & 7) << 4);
        af[mt] = *(const s16x8*)(As + row * 128 + kb);
      }
      #pragma unroll
      for (int nt = 0; nt < 4; ++nt) {
        int row = wc * 64 + nt * 16 + r;
        int kb = (kk * 64 + g * 16) ^ ((row & 7) << 4);
        bf[nt] = *(const s16x8*)(Bs + row * 128 + kb);
      }
      #pragma unroll
      for (int mt = 0; mt < 4; ++mt)
        #pragma unroll
        for (int nt = 0; nt < 4; ++nt)
          acc[mt][nt] = __builtin_amdgcn_mfma_f32_16x16x32_bf16(af[mt], bf[nt], acc[mt][nt], 0, 0, 0);
    }
  }
  #pragma unroll
  for (int nt = 0; nt < 4; ++nt) {
    int col = bn * 128 + wc * 64 + nt * 16 + r;
    float bvv = bias[col];
    #pragma unroll
    for (int mt = 0; mt < 4; ++mt) {
      int row0 = bm * 128 + wr * 64 + mt * 16 + g * 4;
      #pragma unroll
      for (int i = 0; i < 4; ++i) {
        float v = acc[mt][nt][i] + bvv;
        if (WRITE_F32) Cf[(size_t)(row0 + i) * N + col] = v;
        else           Cb[(size_t)(row0 + i) * N + col] = f2bf(v);
      }
    }
  }
}

// ---------------- positional score tables (bf16, base-2 pre-scaled, mask baked into pk) --
__global__ __launch_bounds__(256) void k_pos(const ushort* qkv, const ushort* mask01,
                                             ushort* qp, ushort* pk) {
  int bh = blockIdx.x;
  int b = bh >> 4, h = bh & 15;
  int tid = threadIdx.x, lane = tid & 63, w = tid >> 6;
  int g = lane >> 4, r = lane & 15;
  __shared__ ushort mb[512];
  for (int i = tid; i < 512; i += 256) mb[i] = mask01[b * SEQ + i];
  __syncthreads();
  s16x8 bkp[4][2], bqp[4][2];   // kpos / qpos B-fragments (t = nt*16+r)
  #pragma unroll
  for (int nt = 0; nt < 4; ++nt)
    #pragma unroll
    for (int kk = 0; kk < 2; ++kk) {
      size_t rowp = (size_t)(NROWS + nt * 16 + r);
      int colq = h * 64 + kk * 32 + g * 8;
      bqp[nt][kk] = *(const s16x8*)(qkv + rowp * NQKV + colq);
      bkp[nt][kk] = *(const s16x8*)(qkv + rowp * NQKV + 1024 + colq);
    }
  for (int cc = 0; cc < 8; ++cc) {
    int rowbase = cc * 64 + w * 16;
    s16x8 aq[2], ak[2];
    #pragma unroll
    for (int kk = 0; kk < 2; ++kk) {
      size_t rowq = (size_t)((rowbase + r) * 16 + b);
      int colq = h * 64 + kk * 32 + g * 8;
      aq[kk] = *(const s16x8*)(qkv + rowq * NQKV + colq);
      ak[kk] = *(const s16x8*)(qkv + rowq * NQKV + 1024 + colq);
    }
    f32x4 accq[4] = {}, acck[4] = {};
    #pragma unroll
    for (int kk = 0; kk < 2; ++kk)
      #pragma unroll
      for (int nt = 0; nt < 4; ++nt) {
        accq[nt] = __builtin_amdgcn_mfma_f32_16x16x32_bf16(aq[kk], bkp[nt][kk], accq[nt], 0, 0, 0);
        acck[nt] = __builtin_amdgcn_mfma_f32_16x16x32_bf16(ak[kk], bqp[nt][kk], acck[nt], 0, 0, 0);
      }
    #pragma unroll
    for (int nt = 0; nt < 4; ++nt)
      #pragma unroll
      for (int i = 0; i < 4; ++i) {
        int q = rowbase + g * 4 + i;
        int t = nt * 16 + r;
        float biasv = mb[q] ? -1e9f : 0.0f;          // key-mask baked into pk rows
        qp[(size_t)bh * SEQ * 64 + q * 64 + t] = f2bf(accq[nt][i] * SCALE2);
        pk[(size_t)bh * SEQ * 64 + q * 64 + t] = f2bf(acck[nt][i] * SCALE2 + biasv);
      }
  }
}

// ---------------- V transpose + K repack (K pre-scaled, base-2): vt[b,h,d,l], kc[b,h,l,d]
__global__ __launch_bounds__(256) void k_vt(const ushort* qkv, ushort* vt, ushort* kc) {
  int bid = blockIdx.x;
  int bh = bid >> 3, lt = bid & 7;
  int b = bh >> 4, h = bh & 15;
  __shared__ ushort tile[64][72];
  int tid = threadIdx.x;
  #pragma unroll
  for (int c = 0; c < 2; ++c) {
    int e = (c * 256 + tid) * 8;
    int l = e >> 6, d0 = e & 63;
    size_t row = (size_t)((lt * 64 + l) * 16 + b);
    s16x8 kv = *(const s16x8*)(qkv + row * NQKV + 1024 + h * 64 + d0);
    #pragma unroll
    for (int j = 0; j < 8; ++j) kv[j] = (short)f2bf(bf2f((ushort)kv[j]) * SCALE2);
    *(s16x8*)(kc + ((size_t)bh * SEQ + lt * 64 + l) * 64 + d0) = kv;   // scaled K rows
    *(s16x8*)&tile[l][d0] = *(const s16x8*)(qkv + row * NQKV + 2048 + h * 64 + d0);
  }
  __syncthreads();
  #pragma unroll
  for (int c = 0; c < 2; ++c) {
    int e = (c * 256 + tid) * 8;
    int d = e >> 6, l0 = e & 63;
    ushort tmp[8];
    #pragma unroll
    for (int j = 0; j < 8; ++j) tmp[j] = tile[l0 + j][d];
    *(s16x8*)(vt + (size_t)(bh * 64 + d) * SEQ + lt * 64 + l0) = *(s16x8*)tmp;
  }
}

// ---------------- fused attention: swapped QK^T, 2 q-tiles per 512-thread block ----------
// 8 waves share one Ks/pk_s staging per kt (amortized barriers); stride-68 tables kill the
// R5 bank conflicts; idx as u16; LDS 53,760 -> 3 blocks/CU (24 waves).
// pk staging: exactly ONE s16x8 chunk per thread (512 x 8 = 4096 = 64x64 tile). [R6 bugfix]
__global__ __launch_bounds__(512) void k_attn(const ushort* qkv, const ushort* qp_all, const ushort* pk_all,
                                              const ushort* kc, const ushort* vt,
                                              const int* idx_tab, ushort* ctx) {
  int bid = blockIdx.x;
  int slot = bid >> 3;
  int bh = (bid & 7) * 32 + (slot >> 2);   // all 4 blocks of a bh on one XCD
  int qt0 = (slot & 3) * 2;                // first of two q-tiles
  int b = bh >> 4, h = bh & 15;
  int tid = threadIdx.x, lane = tid & 63, w = tid >> 6;
  int g = lane >> 4, r = lane & 15;
  int qsub = w >> 2, wq = w & 3;           // wave -> (q-tile, quarter)

  __shared__ char   Ks[8192];
  __shared__ ushort qp_s[128][68];
  __shared__ ushort pk_s[64][68];
  __shared__ ushort p_s[8][16][68];
  __shared__ ushort idx_s[1024];

  const size_t qp_base = (size_t)bh * SEQ * 64 + (size_t)qt0 * 4096;
  const size_t pk_base = (size_t)bh * SEQ * 64;
  const char* kcb = (const char*)(kc + (size_t)bh * SEQ * 64);   // [l][d] 128B rows

  int krow = tid >> 3;                               // K staging row (one 16B chunk/thread)
  int ksrccol = ((tid & 7) ^ (krow & 7)) << 4;       // pre-swizzled source col (bytes)
  int prow = tid >> 3, pcol8 = (tid & 7) * 8;        // pk staging coords (one chunk/thread)

  // ---- prologue: stage K(0), pk(0)->regs->LDS, qp->LDS, idx, aq ----
  {
    const char* src = kcb + (size_t)krow * 128 + ksrccol;
    __builtin_amdgcn_global_load_lds((const __attribute__((address_space(1))) void*)src,
                                     (__attribute__((address_space(3))) void*)(Ks + w * 1024),
                                     16, 0, 0);
  }
  s16x8 pkreg = *(const s16x8*)(pk_all + pk_base + (size_t)tid * 8);
  #pragma unroll
  for (int c = 0; c < 4; ++c) {
    int chunk = c * 512 + tid;                 // 2048 chunks of u16x4 = 128 rows x 64
    int row = chunk >> 4, col4 = (chunk & 15) * 4;
    *(u16x4*)&qp_s[row][col4] = *(const u16x4*)(qp_all + qp_base + (size_t)row * 64 + col4);
  }
  for (int i = tid; i < 1023; i += 512) idx_s[i] = (ushort)idx_tab[i];
  s16x8 aq[2];
  int qg0 = (qt0 + qsub) * 64 + wq * 16;
  #pragma unroll
  for (int kk = 0; kk < 2; ++kk) {
    size_t row = (size_t)((qg0 + r) * 16 + b);
    aq[kk] = *(const s16x8*)(qkv + row * NQKV + h * 64 + kk * 32 + g * 8);
  }
  {
    u16x4 lo = { (ushort)pkreg[0], (ushort)pkreg[1], (ushort)pkreg[2], (ushort)pkreg[3] };
    u16x4 hi = { (ushort)pkreg[4], (ushort)pkreg[5], (ushort)pkreg[6], (ushort)pkreg[7] };
    *(u16x4*)&pk_s[prow][pcol8] = lo;
    *(u16x4*)&pk_s[prow][pcol8 + 4] = hi;
  }
  __syncthreads();   // drains K(0) staging too

  float m_i = -3e38f, l_i = 0.0f;
  f32x4 o_acc[4] = {};
  const ushort* qprow = &qp_s[qsub * 64 + wq * 16 + r][0];   // this thread's q-row
  const int qglob511 = (qt0 + qsub) * 64 + wq * 16 + r + 511;

  for (int kt = 0; kt < 8; ++kt) {
    // prefetch pk(kt+1) into regs (consumed after barrier A)
    if (kt < 7)
      pkreg = *(const s16x8*)(pk_all + pk_base + (size_t)(kt + 1) * 4096 + (size_t)tid * 8);

    // ---- swapped QK^T: lane holds S^T for q = r, k = nt*16+g*4+i ----
    f32x4 s[4];
    #pragma unroll
    for (int nt = 0; nt < 4; ++nt) {
      f32x4 a = {};
      #pragma unroll
      for (int kk = 0; kk < 2; ++kk) {
        s16x8 bk = *(const s16x8*)(Ks + (nt * 16 + r) * 128 + ((kk * 64 + g * 16) ^ ((r & 7) << 4)));
        a = __builtin_amdgcn_mfma_f32_16x16x32_bf16(bk, aq[kk], a, 0, 0, 0);   // A=K, B=Q
      }
      s[nt] = a;
    }

    // ---- gather pass: v = c2c + qp[q][t] + pk[k][t]  (base-2 pre-scaled, mask in pk) ----
    float m_loc = -3e38f;
    #pragma unroll
    for (int nt = 0; nt < 4; ++nt) {
      #pragma unroll
      for (int i = 0; i < 4; ++i) {
        int kl = nt * 16 + g * 4 + i;
        int t = idx_s[qglob511 - kt * 64 - kl];
        float v = s[nt][i] + bf2f(qprow[t]) + bf2f(pk_s[kl][t]);
        s[nt][i] = v;
        m_loc = fmaxf(m_loc, v);
      }
    }
    __syncthreads();   // A: all waves done reading Ks + pk_s

    // ---- issue next-tile staging; softmax/PV below covers the latency ----
    if (kt < 7) {
      const char* src = kcb + (size_t)(kt + 1) * 8192 + (size_t)krow * 128 + ksrccol;
      __builtin_amdgcn_global_load_lds((const __attribute__((address_space(1))) void*)src,
                                       (__attribute__((address_space(3))) void*)(Ks + w * 1024),
                                       16, 0, 0);
      u16x4 lo = { (ushort)pkreg[0], (ushort)pkreg[1], (ushort)pkreg[2], (ushort)pkreg[3] };
      u16x4 hi = { (ushort)pkreg[4], (ushort)pkreg[5], (ushort)pkreg[6], (ushort)pkreg[7] };
      *(u16x4*)&pk_s[prow][pcol8] = lo;
      *(u16x4*)&pk_s[prow][pcol8 + 4] = hi;
    }
    // V loads for this tile (latency hidden under softmax)
    s16x8 vreg[2][4];
    #pragma unroll
    for (int kk = 0; kk < 2; ++kk)
      #pragma unroll
      for (int nt = 0; nt < 4; ++nt)
        vreg[kk][nt] = *(const s16x8*)(vt + (size_t)(bh * 64 + nt * 16 + r) * SEQ + kt * 64 + kk * 32 + g * 8);

    // ---- row max across the 4 g-lanes holding q = r ----
    float mx = fmaxf(m_loc, __shfl_xor(m_loc, 16));
    mx = fmaxf(mx, __shfl_xor(mx, 32));

    // ---- T13 defer-rescale (base-2 threshold 8) ----
    if (__any(mx > m_i + 8.0f)) {
      float mnew = fmaxf(m_i, mx);
      float rs = exp2f(m_i - mnew);
      m_i = mnew;
      l_i *= rs;
      float rsb[4];
      #pragma unroll
      for (int i = 0; i < 4; ++i) rsb[i] = __shfl(rs, g * 4 + i);   // rs for q = g*4+i
      #pragma unroll
      for (int nt = 0; nt < 4; ++nt)
        #pragma unroll
        for (int i = 0; i < 4; ++i) o_acc[nt][i] *= rsb[i];
    }

    // ---- exp2 + P pack (b64 LDS writes), psum ----
    float psum = 0.0f;
    #pragma unroll
    for (int nt = 0; nt < 4; ++nt) {
      u16x4 pk4;
      #pragma unroll
      for (int i = 0; i < 4; ++i) {
        float pe = exp2f(s[nt][i] - m_i);   // masked: huge negative -> exact 0
        psum += pe;
        pk4[i] = f2bf(pe);
      }
      *(u16x4*)&p_s[w][r][nt * 16 + g * 4] = pk4;
    }
    psum += __shfl_xor(psum, 16);
    psum += __shfl_xor(psum, 32);
    l_i += psum;

    // ---- PV (p_s re-read as 2 x b64 per fragment) ----
    #pragma unroll
    for (int kk = 0; kk < 2; ++kk) {
      u16x4 lo = *(const u16x4*)&p_s[w][r][kk * 32 + g * 8];
      u16x4 hi = *(const u16x4*)&p_s[w][r][kk * 32 + g * 8 + 4];
      s16x8 pa = { (short)lo[0], (short)lo[1], (short)lo[2], (short)lo[3],
                   (short)hi[0], (short)hi[1], (short)hi[2], (short)hi[3] };
      #pragma unroll
      for (int nt = 0; nt < 4; ++nt)
        o_acc[nt] = __builtin_amdgcn_mfma_f32_16x16x32_bf16(pa, vreg[kk][nt], o_acc[nt], 0, 0, 0);
    }

    if (kt < 7) __syncthreads();   // B: staging + pk_s(kt+1) visible (vmcnt drain overlapped)
  }

  float lb[4];
  #pragma unroll
  for (int i = 0; i < 4; ++i) lb[i] = __shfl(l_i, g * 4 + i);   // l for q = g*4+i
  #pragma unroll
  for (int i = 0; i < 4; ++i) {
    float inv = lb[i] > 0.0f ? 1.0f / lb[i] : 0.0f;
    int lq = (qt0 + qsub) * 64 + wq * 16 + g * 4 + i;
    size_t rowc = (size_t)(lq * 16 + b);
    #pragma unroll
    for (int nt = 0; nt < 4; ++nt)
      ctx[rowc * HID + h * 64 + nt * 16 + r] = f2bf(o_acc[nt][i] * inv);
  }
}

// ---------------- LN2 (affine), bf16 in -> f32 out ---------------------------------------
__global__ __launch_bounds__(256) void k_ln2(const ushort* tmpb, const float* gamma, const float* beta,
                                             float* out) {
  int row = blockIdx.x, tid = threadIdx.x;
  __shared__ float red[8];
  u16x4 xb = *(const u16x4*)(tmpb + (size_t)row * HID + tid * 4);
  float x[4] = { bf2f(xb[0]), bf2f(xb[1]), bf2f(xb[2]), bf2f(xb[3]) };
  float s = x[0] + x[1] + x[2] + x[3];
  #pragma unroll
  for (int m = 1; m < 64; m <<= 1) s += __shfl_xor(s, m);
  if ((tid & 63) == 0) red[tid >> 6] = s;
  __syncthreads();
  float mean = (red[0] + red[1] + red[2] + red[3]) * (1.0f / HID);
  float d[4]; float sq = 0.0f;
  #pragma unroll
  for (int j = 0; j < 4; ++j) { d[j] = x[j] - mean; sq += d[j] * d[j]; }
  #pragma unroll
  for (int m = 1; m < 64; m <<= 1) sq += __shfl_xor(sq, m);
  __syncthreads();
  if ((tid & 63) == 0) red[4 + (tid >> 6)] = sq;
  __syncthreads();
  float var = (red[4] + red[5] + red[6] + red[7]) * (1.0f / HID);
  float rs = rsqrtf(var + LNEPS);
  f32x4 o;
  #pragma unroll
  for (int j = 0; j < 4; ++j) o[j] = d[j] * rs * gamma[tid * 4 + j] + beta[tid * 4 + j];
  *(f32x4*)(out + (size_t)row * HID + tid * 4) = o;
}

// ---------------- launch -----------------------------------------------------------------
extern "C" void kernel_launch(void* const* d_in, const int* in_sizes, int n_in,
                              void* d_out, int out_size, void* d_ws, size_t ws_size,
                              hipStream_t stream) {
  (void)in_sizes; (void)n_in; (void)out_size; (void)ws_size;
  const float* hid  = (const float*)d_in[0];
  const void*  mask = d_in[1];
  const float* rel  = (const float*)d_in[2];
  const float* wqk  = (const float*)d_in[3];
  const float* bqk  = (const float*)d_in[4];
  const float* wv   = (const float*)d_in[5];
  const float* bv   = (const float*)d_in[6];
  const float* wo   = (const float*)d_in[7];
  const float* bo   = (const float*)d_in[8];
  const float* ln_g = (const float*)d_in[9];
  const float* ln_b = (const float*)d_in[10];

  char* ws = (char*)d_ws;
  ushort* wcat     = (ushort*)(ws);                 //  6,291,456
  ushort* wo_b     = (ushort*)(ws + 6291456);       //  2,097,152
  float*  bcat     = (float*) (ws + 8388608);       //     12,288
  ushort* mask01   = (ushort*)(ws + 8400896);       //     16,384 (region 32,768)
  int*    idx_tab  = (int*)   (ws + 8433664);       //      4,096
  ushort* h_ext    = (ushort*)(ws + 8437760);       // 17,039,360  (reused as ctx)
  ushort* qkv      = (ushort*)(ws + 25477120);      // 51,118,080
  ushort* qp_b     = (ushort*)(ws + 76595200);      // 16,777,216 (bf16, base-2 pre-scaled)
  ushort* pk_b     = (ushort*)(ws + 93372416);      // 16,777,216 (bf16, pre-scaled + mask)
  ushort* vt       = (ushort*)(ws + 110149632);     // 16,777,216
  char*   tmpr     = (ws + 126926848);              // 33,554,432 region
  ushort* ctx = h_ext;
  ushort* kc   = (ushort*)tmpr;   // kc[bh][l][d] (scaled) — dead once gemm<1> runs
  ushort* tmpb = (ushort*)tmpr;   // gemm<1> bf16 output overwrites kc (sequential)

  k_prep<<<1, 256, 0, stream>>>(mask, bqk, bv, mask01, idx_tab, bcat);
  k_convert<<<4096, 256, 0, stream>>>(wqk, wv, wo, wcat, wo_b);
  k_ln1<<<MEXT, 256, 0, stream>>>(hid, rel, h_ext);
  k_gemm<0><<<(MEXT / 128) * (NQKV / 128), 256, 0, stream>>>(h_ext, wcat, bcat, qkv, nullptr, MEXT, NQKV, 1024);
  k_pos<<<256, 256, 0, stream>>>(qkv, mask01, qp_b, pk_b);
  k_vt<<<2048, 256, 0, stream>>>(qkv, vt, kc);
  k_attn<<<1024, 512, 0, stream>>>(qkv, qp_b, pk_b, kc, vt, idx_tab, ctx);
  k_gemm<0><<<(NROWS / 128) * (1024 / 128), 256, 0, stream>>>(ctx, wo_b, bo, tmpb, nullptr, NROWS, 1024, 1024);
  k_ln2<<<NROWS, 256, 0, stream>>>(tmpb, ln_g, ln_b, (float*)d_out);
}

// Round 8
// 255.620 us; speedup vs baseline: 1.0992x; 1.0380x over previous
//
#include <hip/hip_runtime.h>
#include <hip/hip_bf16.h>

#define HID 1024
#define HEADS 16
#define HEAD 64
#define RELN 63
#define SEQ 512
#define BATCH 16
#define NROWS (SEQ*BATCH)      // 8192
#define MEXT 8320              // 8192 + 63, padded to 65*128
#define NQKV 3072
#define LNEPS 1e-7f
// 1/sqrt(3*64) * log2(e): all attention-score terms pre-scaled into base-2 domain
#define SCALE2 (0.07216878364870323f * 1.4426950408889634f)

typedef __attribute__((ext_vector_type(4))) float  f32x4;
typedef __attribute__((ext_vector_type(8))) short  s16x8;
typedef __attribute__((ext_vector_type(4))) ushort u16x4;

static __device__ __forceinline__ ushort f2bf(float f) {
  union { float f; unsigned u; } v; v.f = f;
  unsigned r = v.u + 0x7fffu + ((v.u >> 16) & 1u);
  return (ushort)(r >> 16);
}
static __device__ __forceinline__ float bf2f(ushort u) {
  union { unsigned u; float f; } v; v.u = ((unsigned)u) << 16;
  return v.f;
}

// ---------------- prep: mask dtype detect + mask01 + bucket idx table + bias concat ------
__global__ void k_prep(const void* mask_raw, const float* bqk, const float* bv,
                       ushort* mask01, int* idx_tab, float* bcat) {
  __shared__ int s_isbool;
  int tid = threadIdx.x;
  if (tid == 0) s_isbool = 0;
  __syncthreads();
  const unsigned* mu = (const unsigned*)mask_raw;
  int bad = 0;
  for (int i = tid; i < 2048; i += 256) if (mu[i] > 1u) bad = 1;
  if (bad) s_isbool = 1;              // benign race: any writer writes 1
  __syncthreads();
  int isbool = s_isbool;
  const unsigned char* m8 = (const unsigned char*)mask_raw;
  const int* m32 = (const int*)mask_raw;
  for (int i = tid; i < BATCH*SEQ; i += 256) {
    int m = isbool ? (int)m8[i] : m32[i];
    mask01[i] = m ? 1 : 0;
  }
  for (int i = tid; i < 1023; i += 256) {
    int r = i - 511;
    int a = r < 0 ? -r : r;
    int absp = (a < 16) ? 15 : (a < 511 ? a : 511);
    int idx;
    if (absp <= 16) idx = 31 + r;
    else {
      float v = logf((float)absp / 16.0f) / logf(511.0f / 16.0f) * 15.0f;
      int lp = (int)ceilf(v) + 16;
      idx = 31 + (r > 0 ? lp : -lp);
    }
    idx_tab[i] = idx;
  }
  for (int i = tid; i < 2048; i += 256) bcat[i] = bqk[i];
  for (int i = tid; i < 1024; i += 256) bcat[2048 + i] = bv[i];
}

// ---------------- f32 -> bf16 weight conversion, vectorized x4 ---------------------------
__global__ __launch_bounds__(256) void k_convert(const float* wqk, const float* wv, const float* wo,
                                                 ushort* wcat, ushort* wo_b) {
  int c = blockIdx.x * 256 + threadIdx.x;    // 1,048,576 chunks of 4 elems
  f32x4 x; ushort* dst;
  if (c < 524288)      { x = *(const f32x4*)(wqk + (size_t)c * 4);            dst = wcat + (size_t)c * 4; }
  else if (c < 786432) { x = *(const f32x4*)(wv  + (size_t)(c - 524288) * 4); dst = wcat + (size_t)c * 4; }
  else                 { x = *(const f32x4*)(wo  + (size_t)(c - 786432) * 4); dst = wo_b + (size_t)(c - 786432) * 4; }
  u16x4 o = { f2bf(x[0]), f2bf(x[1]), f2bf(x[2]), f2bf(x[3]) };
  *(u16x4*)dst = o;
}

// ---------------- LN1 (no affine) -> bf16, plus rel-embedding rows + zero pad ------------
__global__ __launch_bounds__(256) void k_ln1(const float* hid, const float* rel, ushort* h_ext) {
  int row = blockIdx.x, tid = threadIdx.x;
  __shared__ float red[8];
  if (row < NROWS) {
    const float* src = hid + (size_t)row * HID;
    f32x4 x = *(const f32x4*)(src + tid * 4);
    float s = x[0] + x[1] + x[2] + x[3];
    #pragma unroll
    for (int m = 1; m < 64; m <<= 1) s += __shfl_xor(s, m);
    if ((tid & 63) == 0) red[tid >> 6] = s;
    __syncthreads();
    float mean = (red[0] + red[1] + red[2] + red[3]) * (1.0f / HID);
    float d0 = x[0] - mean, d1 = x[1] - mean, d2 = x[2] - mean, d3 = x[3] - mean;
    float sq = d0*d0 + d1*d1 + d2*d2 + d3*d3;
    #pragma unroll
    for (int m = 1; m < 64; m <<= 1) sq += __shfl_xor(sq, m);
    __syncthreads();
    if ((tid & 63) == 0) red[4 + (tid >> 6)] = sq;
    __syncthreads();
    float var = (red[4] + red[5] + red[6] + red[7]) * (1.0f / HID);
    float rs = rsqrtf(var + LNEPS);
    u16x4 o = { f2bf(d0*rs), f2bf(d1*rs), f2bf(d2*rs), f2bf(d3*rs) };
    *(u16x4*)(h_ext + (size_t)row * HID + tid * 4) = o;
  } else if (row < NROWS + RELN) {
    const float* src = rel + (size_t)(row - NROWS) * HID;
    f32x4 x = *(const f32x4*)(src + tid * 4);
    u16x4 o = { f2bf(x[0]), f2bf(x[1]), f2bf(x[2]), f2bf(x[3]) };
    *(u16x4*)(h_ext + (size_t)row * HID + tid * 4) = o;
  } else {
    u16x4 z = { 0, 0, 0, 0 };
    *(u16x4*)(h_ext + (size_t)row * HID + tid * 4) = z;
  }
}

// ---------------- NT GEMM: C[M,N] = A[M,K] * B[N,K]^T + bias, bf16 in, bf16/f32 out ------
template<int WRITE_F32>
__global__ __launch_bounds__(256) void k_gemm(const ushort* A, const ushort* Bw, const float* bias,
                                              ushort* Cb, float* Cf, int M, int N, int K) {
  __shared__ char smem[32768];
  char* As = smem;
  char* Bs = smem + 16384;
  int tid = threadIdx.x, lane = tid & 63, w = tid >> 6;
  int nbn = N >> 7;
  int per = gridDim.x >> 3;
  int gl = (blockIdx.x & 7) * per + (blockIdx.x >> 3);
  int bm = gl / nbn, bn = gl % nbn;
  int wr = w >> 1, wc = w & 1;
  int g = lane >> 4, r = lane & 15;
  f32x4 acc[4][4] = {};
  for (int ko = 0; ko < K; ko += 64) {
    __syncthreads();
    #pragma unroll
    for (int c = 0; c < 4; ++c) {
      int chunk = c * 256 + tid;
      int row = chunk >> 3;
      int kb = (chunk & 7) << 4;
      int kbs = kb ^ ((row & 7) << 4);   // pre-swizzled source column (bytes)
      const char* gA = (const char*)(A + (size_t)(bm * 128 + row) * K + ko) + kbs;
      const char* gB = (const char*)(Bw + (size_t)(bn * 128 + row) * K + ko) + kbs;
      __builtin_amdgcn_global_load_lds((const __attribute__((address_space(1))) void*)gA,
                                       (__attribute__((address_space(3))) void*)(As + c * 4096 + w * 1024),
                                       16, 0, 0);
      __builtin_amdgcn_global_load_lds((const __attribute__((address_space(1))) void*)gB,
                                       (__attribute__((address_space(3))) void*)(Bs + c * 4096 + w * 1024),
                                       16, 0, 0);
    }
    __syncthreads();
    #pragma unroll
    for (int kk = 0; kk < 2; ++kk) {
      s16x8 af[4], bf[4];
      #pragma unroll
      for (int mt = 0; mt < 4; ++mt) {
        int row = wr * 64 + mt * 16 + r;
        int kb = (kk * 64 + g * 16) ^ ((row & 7) << 4);
        af[mt] = *(const s16x8*)(As + row * 128 + kb);
      }
      #pragma unroll
      for (int nt = 0; nt < 4; ++nt) {
        int row = wc * 64 + nt * 16 + r;
        int kb = (kk * 64 + g * 16) ^ ((row & 7) << 4);
        bf[nt] = *(const s16x8*)(Bs + row * 128 + kb);
      }
      #pragma unroll
      for (int mt = 0; mt < 4; ++mt)
        #pragma unroll
        for (int nt = 0; nt < 4; ++nt)
          acc[mt][nt] = __builtin_amdgcn_mfma_f32_16x16x32_bf16(af[mt], bf[nt], acc[mt][nt], 0, 0, 0);
    }
  }
  #pragma unroll
  for (int nt = 0; nt < 4; ++nt) {
    int col = bn * 128 + wc * 64 + nt * 16 + r;
    float bvv = bias[col];
    #pragma unroll
    for (int mt = 0; mt < 4; ++mt) {
      int row0 = bm * 128 + wr * 64 + mt * 16 + g * 4;
      #pragma unroll
      for (int i = 0; i < 4; ++i) {
        float v = acc[mt][nt][i] + bvv;
        if (WRITE_F32) Cf[(size_t)(row0 + i) * N + col] = v;
        else           Cb[(size_t)(row0 + i) * N + col] = f2bf(v);
      }
    }
  }
}

// ---------------- positional score tables (bf16, base-2 pre-scaled, mask baked into pk) --
__global__ __launch_bounds__(256) void k_pos(const ushort* qkv, const ushort* mask01,
                                             ushort* qp, ushort* pk) {
  int bh = blockIdx.x;
  int b = bh >> 4, h = bh & 15;
  int tid = threadIdx.x, lane = tid & 63, w = tid >> 6;
  int g = lane >> 4, r = lane & 15;
  __shared__ ushort mb[512];
  for (int i = tid; i < 512; i += 256) mb[i] = mask01[b * SEQ + i];
  __syncthreads();
  s16x8 bkp[4][2], bqp[4][2];   // kpos / qpos B-fragments (t = nt*16+r)
  #pragma unroll
  for (int nt = 0; nt < 4; ++nt)
    #pragma unroll
    for (int kk = 0; kk < 2; ++kk) {
      size_t rowp = (size_t)(NROWS + nt * 16 + r);
      int colq = h * 64 + kk * 32 + g * 8;
      bqp[nt][kk] = *(const s16x8*)(qkv + rowp * NQKV + colq);
      bkp[nt][kk] = *(const s16x8*)(qkv + rowp * NQKV + 1024 + colq);
    }
  for (int cc = 0; cc < 8; ++cc) {
    int rowbase = cc * 64 + w * 16;
    s16x8 aq[2], ak[2];
    #pragma unroll
    for (int kk = 0; kk < 2; ++kk) {
      size_t rowq = (size_t)((rowbase + r) * 16 + b);
      int colq = h * 64 + kk * 32 + g * 8;
      aq[kk] = *(const s16x8*)(qkv + rowq * NQKV + colq);
      ak[kk] = *(const s16x8*)(qkv + rowq * NQKV + 1024 + colq);
    }
    f32x4 accq[4] = {}, acck[4] = {};
    #pragma unroll
    for (int kk = 0; kk < 2; ++kk)
      #pragma unroll
      for (int nt = 0; nt < 4; ++nt) {
        accq[nt] = __builtin_amdgcn_mfma_f32_16x16x32_bf16(aq[kk], bkp[nt][kk], accq[nt], 0, 0, 0);
        acck[nt] = __builtin_amdgcn_mfma_f32_16x16x32_bf16(ak[kk], bqp[nt][kk], acck[nt], 0, 0, 0);
      }
    #pragma unroll
    for (int nt = 0; nt < 4; ++nt)
      #pragma unroll
      for (int i = 0; i < 4; ++i) {
        int q = rowbase + g * 4 + i;
        int t = nt * 16 + r;
        float biasv = mb[q] ? -1e9f : 0.0f;          // key-mask baked into pk rows
        qp[(size_t)bh * SEQ * 64 + q * 64 + t] = f2bf(accq[nt][i] * SCALE2);
        pk[(size_t)bh * SEQ * 64 + q * 64 + t] = f2bf(acck[nt][i] * SCALE2 + biasv);
      }
  }
}

// ---------------- V transpose + K repack (K pre-scaled, base-2): vt[b,h,d,l], kc[b,h,l,d]
__global__ __launch_bounds__(256) void k_vt(const ushort* qkv, ushort* vt, ushort* kc) {
  int bid = blockIdx.x;
  int bh = bid >> 3, lt = bid & 7;
  int b = bh >> 4, h = bh & 15;
  __shared__ ushort tile[64][72];
  int tid = threadIdx.x;
  #pragma unroll
  for (int c = 0; c < 2; ++c) {
    int e = (c * 256 + tid) * 8;
    int l = e >> 6, d0 = e & 63;
    size_t row = (size_t)((lt * 64 + l) * 16 + b);
    s16x8 kv = *(const s16x8*)(qkv + row * NQKV + 1024 + h * 64 + d0);
    #pragma unroll
    for (int j = 0; j < 8; ++j) kv[j] = (short)f2bf(bf2f((ushort)kv[j]) * SCALE2);
    *(s16x8*)(kc + ((size_t)bh * SEQ + lt * 64 + l) * 64 + d0) = kv;   // scaled K rows
    *(s16x8*)&tile[l][d0] = *(const s16x8*)(qkv + row * NQKV + 2048 + h * 64 + d0);
  }
  __syncthreads();
  #pragma unroll
  for (int c = 0; c < 2; ++c) {
    int e = (c * 256 + tid) * 8;
    int d = e >> 6, l0 = e & 63;
    ushort tmp[8];
    #pragma unroll
    for (int j = 0; j < 8; ++j) tmp[j] = tile[l0 + j][d];
    *(s16x8*)(vt + (size_t)(bh * 64 + d) * SEQ + lt * 64 + l0) = *(s16x8*)tmp;
  }
}

// ---------------- fused attention: BARRIER-FREE main loop --------------------------------
// Block = (bh, q-half): pk table for ALL 512 k + qp for 256 q staged ONCE (123.9 KB LDS);
// K/V fragments read directly from global (kc/vt, L2-resident, shared by all 8 waves).
// Main loop has ZERO __syncthreads(): waves run independently, stalls overlap.
__global__ __launch_bounds__(512) void k_attn(const ushort* qkv, const ushort* qp_all, const ushort* pk_all,
                                              const ushort* kc, const ushort* vt,
                                              const int* idx_tab, ushort* ctx) {
  int bid = blockIdx.x;
  int slot = bid >> 3;
  int bh = (bid & 7) * 32 + (slot >> 1);   // both q-halves of a bh on one XCD
  int qh = slot & 1;                       // which 256-row q half
  int b = bh >> 4, h = bh & 15;
  int tid = threadIdx.x, lane = tid & 63, w = tid >> 6;
  int g = lane >> 4, r = lane & 15;

  __shared__ ushort pk_f[512][68];   // 69,632 B  full-k pk table
  __shared__ ushort qp_s[256][68];   // 34,816 B  this half's qp rows
  __shared__ ushort p_s[8][16][68];  // 17,408 B  per-wave P staging
  __shared__ ushort idx_s[1024];     //  2,048 B  -> total 123,904 B

  const ushort* qpsrc = qp_all + (size_t)bh * SEQ * 64 + (size_t)qh * 256 * 64;
  const ushort* pksrc = pk_all + (size_t)bh * SEQ * 64;
  const char*   kcb   = (const char*)(kc + (size_t)bh * SEQ * 64);   // [l][d] 128B rows

  // ---- prologue: stage qp(256 rows), pk(512 rows), idx; load aq; ONE barrier ----
  #pragma unroll
  for (int c = 0; c < 4; ++c) {            // qp: 2048 chunks of 8 u16
    int chunk = c * 512 + tid;
    int row = chunk >> 3, col8 = (chunk & 7) * 8;
    s16x8 v = *(const s16x8*)(qpsrc + (size_t)row * 64 + col8);
    u16x4 lo = { (ushort)v[0], (ushort)v[1], (ushort)v[2], (ushort)v[3] };
    u16x4 hi = { (ushort)v[4], (ushort)v[5], (ushort)v[6], (ushort)v[7] };
    *(u16x4*)&qp_s[row][col8] = lo;
    *(u16x4*)&qp_s[row][col8 + 4] = hi;
  }
  #pragma unroll
  for (int c = 0; c < 8; ++c) {            // pk: 4096 chunks of 8 u16
    int chunk = c * 512 + tid;
    int row = chunk >> 3, col8 = (chunk & 7) * 8;
    s16x8 v = *(const s16x8*)(pksrc + (size_t)row * 64 + col8);
    u16x4 lo = { (ushort)v[0], (ushort)v[1], (ushort)v[2], (ushort)v[3] };
    u16x4 hi = { (ushort)v[4], (ushort)v[5], (ushort)v[6], (ushort)v[7] };
    *(u16x4*)&pk_f[row][col8] = lo;
    *(u16x4*)&pk_f[row][col8 + 4] = hi;
  }
  for (int i = tid; i < 1023; i += 512) idx_s[i] = (ushort)idx_tab[i];
  s16x8 aq[2][2];                          // [qs][kk] Q fragments for this wave's 2 subtiles
  #pragma unroll
  for (int qs = 0; qs < 2; ++qs)
    #pragma unroll
    for (int kk = 0; kk < 2; ++kk) {
      int qglob = qh * 256 + qs * 128 + w * 16 + r;
      aq[qs][kk] = *(const s16x8*)(qkv + ((size_t)qglob * 16 + b) * NQKV + h * 64 + kk * 32 + g * 8);
    }
  __syncthreads();   // the ONLY barrier

  float m_i[2] = { -3e38f, -3e38f }, l_i[2] = { 0.0f, 0.0f };
  f32x4 o_acc[2][4] = {};

  for (int kt = 0; kt < 8; ++kt) {
    // K and V fragments straight from global (L2-shared across the block's 8 waves)
    s16x8 kf[4][2], vf[2][4];
    #pragma unroll
    for (int nt = 0; nt < 4; ++nt)
      #pragma unroll
      for (int kk = 0; kk < 2; ++kk)
        kf[nt][kk] = *(const s16x8*)(kcb + (size_t)(kt * 64 + nt * 16 + r) * 128 + kk * 64 + g * 16);
    #pragma unroll
    for (int kk = 0; kk < 2; ++kk)
      #pragma unroll
      for (int nt = 0; nt < 4; ++nt)
        vf[kk][nt] = *(const s16x8*)(vt + (size_t)(bh * 64 + nt * 16 + r) * SEQ + kt * 64 + kk * 32 + g * 8);

    #pragma unroll
    for (int qs = 0; qs < 2; ++qs) {
      // ---- swapped QK^T: lane holds S^T for q = r, k = nt*16+g*4+i ----
      f32x4 s[4];
      #pragma unroll
      for (int nt = 0; nt < 4; ++nt) {
        f32x4 a = {};
        #pragma unroll
        for (int kk = 0; kk < 2; ++kk)
          a = __builtin_amdgcn_mfma_f32_16x16x32_bf16(kf[nt][kk], aq[qs][kk], a, 0, 0, 0);   // A=K, B=Q
        s[nt] = a;
      }

      // ---- gather: v = c2c + qp[q][t] + pk[k][t]  (base-2 pre-scaled, mask in pk) ----
      const ushort* qprow = &qp_s[qs * 128 + w * 16 + r][0];
      const int qg511 = qh * 256 + qs * 128 + w * 16 + r + 511;
      float m_loc = -3e38f;
      #pragma unroll
      for (int nt = 0; nt < 4; ++nt) {
        #pragma unroll
        for (int i = 0; i < 4; ++i) {
          int kg = kt * 64 + nt * 16 + g * 4 + i;
          int t = idx_s[qg511 - kg];
          float v = s[nt][i] + bf2f(qprow[t]) + bf2f(pk_f[kg][t]);
          s[nt][i] = v;
          m_loc = fmaxf(m_loc, v);
        }
      }

      // ---- row max across the 4 g-lanes holding q = r ----
      float mx = fmaxf(m_loc, __shfl_xor(m_loc, 16));
      mx = fmaxf(mx, __shfl_xor(mx, 32));

      // ---- T13 defer-rescale (base-2 threshold 8) ----
      if (__any(mx > m_i[qs] + 8.0f)) {
        float mnew = fmaxf(m_i[qs], mx);
        float rs = exp2f(m_i[qs] - mnew);
        m_i[qs] = mnew;
        l_i[qs] *= rs;
        float rsb[4];
        #pragma unroll
        for (int i = 0; i < 4; ++i) rsb[i] = __shfl(rs, g * 4 + i);   // rs for q = g*4+i
        #pragma unroll
        for (int nt = 0; nt < 4; ++nt)
          #pragma unroll
          for (int i = 0; i < 4; ++i) o_acc[qs][nt][i] *= rsb[i];
      }

      // ---- exp2 + P pack (b64 LDS writes), psum ----
      float psum = 0.0f;
      #pragma unroll
      for (int nt = 0; nt < 4; ++nt) {
        u16x4 pk4;
        #pragma unroll
        for (int i = 0; i < 4; ++i) {
          float pe = exp2f(s[nt][i] - m_i[qs]);   // masked: huge negative -> exact 0
          psum += pe;
          pk4[i] = f2bf(pe);
        }
        *(u16x4*)&p_s[w][r][nt * 16 + g * 4] = pk4;
      }
      psum += __shfl_xor(psum, 16);
      psum += __shfl_xor(psum, 32);
      l_i[qs] += psum;

      // ---- PV (per-wave p_s roundtrip, ordered by lgkmcnt within the wave) ----
      #pragma unroll
      for (int kk = 0; kk < 2; ++kk) {
        u16x4 lo = *(const u16x4*)&p_s[w][r][kk * 32 + g * 8];
        u16x4 hi = *(const u16x4*)&p_s[w][r][kk * 32 + g * 8 + 4];
        s16x8 pa = { (short)lo[0], (short)lo[1], (short)lo[2], (short)lo[3],
                     (short)hi[0], (short)hi[1], (short)hi[2], (short)hi[3] };
        #pragma unroll
        for (int nt = 0; nt < 4; ++nt)
          o_acc[qs][nt] = __builtin_amdgcn_mfma_f32_16x16x32_bf16(pa, vf[kk][nt], o_acc[qs][nt], 0, 0, 0);
      }
    }
  }

  #pragma unroll
  for (int qs = 0; qs < 2; ++qs) {
    float lb[4];
    #pragma unroll
    for (int i = 0; i < 4; ++i) lb[i] = __shfl(l_i[qs], g * 4 + i);   // l for q = g*4+i
    #pragma unroll
    for (int i = 0; i < 4; ++i) {
      float inv = lb[i] > 0.0f ? 1.0f / lb[i] : 0.0f;
      int lq = qh * 256 + qs * 128 + w * 16 + g * 4 + i;
      size_t rowc = (size_t)(lq * 16 + b);
      #pragma unroll
      for (int nt = 0; nt < 4; ++nt)
        ctx[rowc * HID + h * 64 + nt * 16 + r] = f2bf(o_acc[qs][nt][i] * inv);
    }
  }
}

// ---------------- LN2 (affine), bf16 in -> f32 out ---------------------------------------
__global__ __launch_bounds__(256) void k_ln2(const ushort* tmpb, const float* gamma, const float* beta,
                                             float* out) {
  int row = blockIdx.x, tid = threadIdx.x;
  __shared__ float red[8];
  u16x4 xb = *(const u16x4*)(tmpb + (size_t)row * HID + tid * 4);
  float x[4] = { bf2f(xb[0]), bf2f(xb[1]), bf2f(xb[2]), bf2f(xb[3]) };
  float s = x[0] + x[1] + x[2] + x[3];
  #pragma unroll
  for (int m = 1; m < 64; m <<= 1) s += __shfl_xor(s, m);
  if ((tid & 63) == 0) red[tid >> 6] = s;
  __syncthreads();
  float mean = (red[0] + red[1] + red[2] + red[3]) * (1.0f / HID);
  float d[4]; float sq = 0.0f;
  #pragma unroll
  for (int j = 0; j < 4; ++j) { d[j] = x[j] - mean; sq += d[j] * d[j]; }
  #pragma unroll
  for (int m = 1; m < 64; m <<= 1) sq += __shfl_xor(sq, m);
  __syncthreads();
  if ((tid & 63) == 0) red[4 + (tid >> 6)] = sq;
  __syncthreads();
  float var = (red[4] + red[5] + red[6] + red[7]) * (1.0f / HID);
  float rs = rsqrtf(var + LNEPS);
  f32x4 o;
  #pragma unroll
  for (int j = 0; j < 4; ++j) o[j] = d[j] * rs * gamma[tid * 4 + j] + beta[tid * 4 + j];
  *(f32x4*)(out + (size_t)row * HID + tid * 4) = o;
}

// ---------------- launch -----------------------------------------------------------------
extern "C" void kernel_launch(void* const* d_in, const int* in_sizes, int n_in,
                              void* d_out, int out_size, void* d_ws, size_t ws_size,
                              hipStream_t stream) {
  (void)in_sizes; (void)n_in; (void)out_size; (void)ws_size;
  const float* hid  = (const float*)d_in[0];
  const void*  mask = d_in[1];
  const float* rel  = (const float*)d_in[2];
  const float* wqk  = (const float*)d_in[3];
  const float* bqk  = (const float*)d_in[4];
  const float* wv   = (const float*)d_in[5];
  const float* bv   = (const float*)d_in[6];
  const float* wo   = (const float*)d_in[7];
  const float* bo   = (const float*)d_in[8];
  const float* ln_g = (const float*)d_in[9];
  const float* ln_b = (const float*)d_in[10];

  char* ws = (char*)d_ws;
  ushort* wcat     = (ushort*)(ws);                 //  6,291,456
  ushort* wo_b     = (ushort*)(ws + 6291456);       //  2,097,152
  float*  bcat     = (float*) (ws + 8388608);       //     12,288
  ushort* mask01   = (ushort*)(ws + 8400896);       //     16,384 (region 32,768)
  int*    idx_tab  = (int*)   (ws + 8433664);       //      4,096
  ushort* h_ext    = (ushort*)(ws + 8437760);       // 17,039,360  (reused as ctx)
  ushort* qkv      = (ushort*)(ws + 25477120);      // 51,118,080
  ushort* qp_b     = (ushort*)(ws + 76595200);      // 16,777,216 (bf16, base-2 pre-scaled)
  ushort* pk_b     = (ushort*)(ws + 93372416);      // 16,777,216 (bf16, pre-scaled + mask)
  ushort* vt       = (ushort*)(ws + 110149632);     // 16,777,216
  char*   tmpr     = (ws + 126926848);              // 33,554,432 region
  ushort* ctx = h_ext;
  ushort* kc   = (ushort*)tmpr;   // kc[bh][l][d] (scaled) — dead once gemm<1> runs
  ushort* tmpb = (ushort*)tmpr;   // gemm<1> bf16 output overwrites kc (sequential)

  k_prep<<<1, 256, 0, stream>>>(mask, bqk, bv, mask01, idx_tab, bcat);
  k_convert<<<4096, 256, 0, stream>>>(wqk, wv, wo, wcat, wo_b);
  k_ln1<<<MEXT, 256, 0, stream>>>(hid, rel, h_ext);
  k_gemm<0><<<(MEXT / 128) * (NQKV / 128), 256, 0, stream>>>(h_ext, wcat, bcat, qkv, nullptr, MEXT, NQKV, 1024);
  k_pos<<<256, 256, 0, stream>>>(qkv, mask01, qp_b, pk_b);
  k_vt<<<2048, 256, 0, stream>>>(qkv, vt, kc);
  k_attn<<<512, 512, 0, stream>>>(qkv, qp_b, pk_b, kc, vt, idx_tab, ctx);
  k_gemm<0><<<(NROWS / 128) * (1024 / 128), 256, 0, stream>>>(ctx, wo_b, bo, tmpb, nullptr, NROWS, 1024, 1024);
  k_ln2<<<NROWS, 256, 0, stream>>>(tmpb, ln_g, ln_b, (float*)d_out);
}

// Round 9
// 255.054 us; speedup vs baseline: 1.1016x; 1.0022x over previous
//
#include <hip/hip_runtime.h>
#include <hip/hip_bf16.h>

#define HID 1024
#define HEADS 16
#define HEAD 64
#define RELN 63
#define SEQ 512
#define BATCH 16
#define NROWS (SEQ*BATCH)      // 8192
#define MEXT 8320              // 8192 + 63, padded to 65*128
#define NQKV 3072
#define LNEPS 1e-7f
// 1/sqrt(3*64) * log2(e): all attention-score terms pre-scaled into base-2 domain
#define SCALE2 (0.07216878364870323f * 1.4426950408889634f)

typedef __attribute__((ext_vector_type(4))) float  f32x4;
typedef __attribute__((ext_vector_type(8))) short  s16x8;
typedef __attribute__((ext_vector_type(4))) ushort u16x4;

static __device__ __forceinline__ ushort f2bf(float f) {
  union { float f; unsigned u; } v; v.f = f;
  unsigned r = v.u + 0x7fffu + ((v.u >> 16) & 1u);
  return (ushort)(r >> 16);
}
static __device__ __forceinline__ float bf2f(ushort u) {
  union { unsigned u; float f; } v; v.u = ((unsigned)u) << 16;
  return v.f;
}

// ---------------- prep: mask dtype detect + mask01 + bucket idx table + bias concat ------
__global__ void k_prep(const void* mask_raw, const float* bqk, const float* bv,
                       ushort* mask01, int* idx_tab, float* bcat) {
  __shared__ int s_isbool;
  int tid = threadIdx.x;
  if (tid == 0) s_isbool = 0;
  __syncthreads();
  const unsigned* mu = (const unsigned*)mask_raw;
  int bad = 0;
  for (int i = tid; i < 2048; i += 256) if (mu[i] > 1u) bad = 1;
  if (bad) s_isbool = 1;              // benign race: any writer writes 1
  __syncthreads();
  int isbool = s_isbool;
  const unsigned char* m8 = (const unsigned char*)mask_raw;
  const int* m32 = (const int*)mask_raw;
  for (int i = tid; i < BATCH*SEQ; i += 256) {
    int m = isbool ? (int)m8[i] : m32[i];
    mask01[i] = m ? 1 : 0;
  }
  for (int i = tid; i < 1023; i += 256) {
    int r = i - 511;
    int a = r < 0 ? -r : r;
    int absp = (a < 16) ? 15 : (a < 511 ? a : 511);
    int idx;
    if (absp <= 16) idx = 31 + r;
    else {
      float v = logf((float)absp / 16.0f) / logf(511.0f / 16.0f) * 15.0f;
      int lp = (int)ceilf(v) + 16;
      idx = 31 + (r > 0 ? lp : -lp);
    }
    idx_tab[i] = idx;
  }
  for (int i = tid; i < 2048; i += 256) bcat[i] = bqk[i];
  for (int i = tid; i < 1024; i += 256) bcat[2048 + i] = bv[i];
}

// ---------------- f32 -> bf16 weight conversion, vectorized x4 ---------------------------
__global__ __launch_bounds__(256) void k_convert(const float* wqk, const float* wv, const float* wo,
                                                 ushort* wcat, ushort* wo_b) {
  int c = blockIdx.x * 256 + threadIdx.x;    // 1,048,576 chunks of 4 elems
  f32x4 x; ushort* dst;
  if (c < 524288)      { x = *(const f32x4*)(wqk + (size_t)c * 4);            dst = wcat + (size_t)c * 4; }
  else if (c < 786432) { x = *(const f32x4*)(wv  + (size_t)(c - 524288) * 4); dst = wcat + (size_t)c * 4; }
  else                 { x = *(const f32x4*)(wo  + (size_t)(c - 786432) * 4); dst = wo_b + (size_t)(c - 786432) * 4; }
  u16x4 o = { f2bf(x[0]), f2bf(x[1]), f2bf(x[2]), f2bf(x[3]) };
  *(u16x4*)dst = o;
}

// ---------------- LN1 (no affine) -> bf16, plus rel-embedding rows + zero pad ------------
__global__ __launch_bounds__(256) void k_ln1(const float* hid, const float* rel, ushort* h_ext) {
  int row = blockIdx.x, tid = threadIdx.x;
  __shared__ float red[8];
  if (row < NROWS) {
    const float* src = hid + (size_t)row * HID;
    f32x4 x = *(const f32x4*)(src + tid * 4);
    float s = x[0] + x[1] + x[2] + x[3];
    #pragma unroll
    for (int m = 1; m < 64; m <<= 1) s += __shfl_xor(s, m);
    if ((tid & 63) == 0) red[tid >> 6] = s;
    __syncthreads();
    float mean = (red[0] + red[1] + red[2] + red[3]) * (1.0f / HID);
    float d0 = x[0] - mean, d1 = x[1] - mean, d2 = x[2] - mean, d3 = x[3] - mean;
    float sq = d0*d0 + d1*d1 + d2*d2 + d3*d3;
    #pragma unroll
    for (int m = 1; m < 64; m <<= 1) sq += __shfl_xor(sq, m);
    __syncthreads();
    if ((tid & 63) == 0) red[4 + (tid >> 6)] = sq;
    __syncthreads();
    float var = (red[4] + red[5] + red[6] + red[7]) * (1.0f / HID);
    float rs = rsqrtf(var + LNEPS);
    u16x4 o = { f2bf(d0*rs), f2bf(d1*rs), f2bf(d2*rs), f2bf(d3*rs) };
    *(u16x4*)(h_ext + (size_t)row * HID + tid * 4) = o;
  } else if (row < NROWS + RELN) {
    const float* src = rel + (size_t)(row - NROWS) * HID;
    f32x4 x = *(const f32x4*)(src + tid * 4);
    u16x4 o = { f2bf(x[0]), f2bf(x[1]), f2bf(x[2]), f2bf(x[3]) };
    *(u16x4*)(h_ext + (size_t)row * HID + tid * 4) = o;
  } else {
    u16x4 z = { 0, 0, 0, 0 };
    *(u16x4*)(h_ext + (size_t)row * HID + tid * 4) = z;
  }
}

// ---------------- QKV GEMM: 256x128 tile, 8 waves, BK=64, swizzled global_load_lds -------
// A rows clamped to M-1 for the partial last tile; C stores guarded by row < M.
__global__ __launch_bounds__(512) void k_gemm256(const ushort* A, const ushort* Bw, const float* bias,
                                                 ushort* Cb, int M, int N, int K) {
  __shared__ char smem[49152];
  char* As = smem;              // 256 x 64 bf16 = 32 KB
  char* Bs = smem + 32768;      // 128 x 64 bf16 = 16 KB
  int tid = threadIdx.x, lane = tid & 63, w = tid >> 6;
  int nbn = N >> 7;
  int per = gridDim.x >> 3;
  int gl = (blockIdx.x & 7) * per + (blockIdx.x >> 3);
  int bm = gl / nbn, bn = gl % nbn;
  int wr = w >> 1, wc = w & 1;           // 4x2 wave grid, 64x64 per wave
  int g = lane >> 4, r = lane & 15;
  f32x4 acc[4][4] = {};
  for (int ko = 0; ko < K; ko += 64) {
    __syncthreads();
    #pragma unroll
    for (int c = 0; c < 4; ++c) {        // A: 2048 chunks of 16B
      int chunk = c * 512 + tid;
      int row = chunk >> 3;
      int kbs = ((chunk & 7) << 4) ^ ((row & 7) << 4);
      int ar = bm * 256 + row; ar = ar < M ? ar : M - 1;
      const char* gA = (const char*)(A + (size_t)ar * K + ko) + kbs;
      __builtin_amdgcn_global_load_lds((const __attribute__((address_space(1))) void*)gA,
                                       (__attribute__((address_space(3))) void*)(As + c * 8192 + w * 1024),
                                       16, 0, 0);
    }
    #pragma unroll
    for (int c = 0; c < 2; ++c) {        // B: 1024 chunks of 16B
      int chunk = c * 512 + tid;
      int row = chunk >> 3;
      int kbs = ((chunk & 7) << 4) ^ ((row & 7) << 4);
      const char* gB = (const char*)(Bw + (size_t)(bn * 128 + row) * K + ko) + kbs;
      __builtin_amdgcn_global_load_lds((const __attribute__((address_space(1))) void*)gB,
                                       (__attribute__((address_space(3))) void*)(Bs + c * 8192 + w * 1024),
                                       16, 0, 0);
    }
    __syncthreads();
    #pragma unroll
    for (int kk = 0; kk < 2; ++kk) {
      s16x8 af[4], bf[4];
      #pragma unroll
      for (int mt = 0; mt < 4; ++mt) {
        int row = wr * 64 + mt * 16 + r;
        int kb = (kk * 64 + g * 16) ^ ((row & 7) << 4);
        af[mt] = *(const s16x8*)(As + row * 128 + kb);
      }
      #pragma unroll
      for (int nt = 0; nt < 4; ++nt) {
        int row = wc * 64 + nt * 16 + r;
        int kb = (kk * 64 + g * 16) ^ ((row & 7) << 4);
        bf[nt] = *(const s16x8*)(Bs + row * 128 + kb);
      }
      #pragma unroll
      for (int mt = 0; mt < 4; ++mt)
        #pragma unroll
        for (int nt = 0; nt < 4; ++nt)
          acc[mt][nt] = __builtin_amdgcn_mfma_f32_16x16x32_bf16(af[mt], bf[nt], acc[mt][nt], 0, 0, 0);
    }
  }
  #pragma unroll
  for (int nt = 0; nt < 4; ++nt) {
    int col = bn * 128 + wc * 64 + nt * 16 + r;
    float bvv = bias[col];
    #pragma unroll
    for (int mt = 0; mt < 4; ++mt) {
      int row0 = bm * 256 + wr * 64 + mt * 16 + g * 4;
      #pragma unroll
      for (int i = 0; i < 4; ++i) {
        int row = row0 + i;
        if (row < M) Cb[(size_t)row * N + col] = f2bf(acc[mt][nt][i] + bvv);
      }
    }
  }
}

// ---------------- output GEMM: 128x128 tile, split-K=2, bf16 partials --------------------
// grid = 64 (bm) x 8 (bn) x 2 (ks); bias added only in ks=0 partial.
__global__ __launch_bounds__(256) void k_gemm_sk(const ushort* A, const ushort* Bw, const float* bias,
                                                 ushort* C0, ushort* C1) {
  const int N = 1024, K = 1024;
  __shared__ char smem[32768];
  char* As = smem;
  char* Bs = smem + 16384;
  int tid = threadIdx.x, lane = tid & 63, w = tid >> 6;
  int per = gridDim.x >> 3;
  int gl = (blockIdx.x & 7) * per + (blockIdx.x >> 3);
  int bn = gl & 7, ks = (gl >> 3) & 1, bm = gl >> 4;
  int wr = w >> 1, wc = w & 1;
  int g = lane >> 4, r = lane & 15;
  f32x4 acc[4][4] = {};
  for (int ko = ks * 512; ko < ks * 512 + 512; ko += 64) {
    __syncthreads();
    #pragma unroll
    for (int c = 0; c < 4; ++c) {
      int chunk = c * 256 + tid;
      int row = chunk >> 3;
      int kbs = ((chunk & 7) << 4) ^ ((row & 7) << 4);
      const char* gA = (const char*)(A + (size_t)(bm * 128 + row) * K + ko) + kbs;
      const char* gB = (const char*)(Bw + (size_t)(bn * 128 + row) * K + ko) + kbs;
      __builtin_amdgcn_global_load_lds((const __attribute__((address_space(1))) void*)gA,
                                       (__attribute__((address_space(3))) void*)(As + c * 4096 + w * 1024),
                                       16, 0, 0);
      __builtin_amdgcn_global_load_lds((const __attribute__((address_space(1))) void*)gB,
                                       (__attribute__((address_space(3))) void*)(Bs + c * 4096 + w * 1024),
                                       16, 0, 0);
    }
    __syncthreads();
    #pragma unroll
    for (int kk = 0; kk < 2; ++kk) {
      s16x8 af[4], bf[4];
      #pragma unroll
      for (int mt = 0; mt < 4; ++mt) {
        int row = wr * 64 + mt * 16 + r;
        int kb = (kk * 64 + g * 16) ^ ((row & 7) << 4);
        af[mt] = *(const s16x8*)(As + row * 128 + kb);
      }
      #pragma unroll
      for (int nt = 0; nt < 4; ++nt) {
        int row = wc * 64 + nt * 16 + r;
        int kb = (kk * 64 + g * 16) ^ ((row & 7) << 4);
        bf[nt] = *(const s16x8*)(Bs + row * 128 + kb);
      }
      #pragma unroll
      for (int mt = 0; mt < 4; ++mt)
        #pragma unroll
        for (int nt = 0; nt < 4; ++nt)
          acc[mt][nt] = __builtin_amdgcn_mfma_f32_16x16x32_bf16(af[mt], bf[nt], acc[mt][nt], 0, 0, 0);
    }
  }
  ushort* C = ks ? C1 : C0;
  #pragma unroll
  for (int nt = 0; nt < 4; ++nt) {
    int col = bn * 128 + wc * 64 + nt * 16 + r;
    float bvv = ks ? 0.0f : bias[col];
    #pragma unroll
    for (int mt = 0; mt < 4; ++mt) {
      int row0 = bm * 128 + wr * 64 + mt * 16 + g * 4;
      #pragma unroll
      for (int i = 0; i < 4; ++i)
        C[(size_t)(row0 + i) * N + col] = f2bf(acc[mt][nt][i] + bvv);
    }
  }
}

// ---------------- positional score tables (bf16, base-2 pre-scaled, mask baked into pk) --
__global__ __launch_bounds__(256) void k_pos(const ushort* qkv, const ushort* mask01,
                                             ushort* qp, ushort* pk) {
  int bh = blockIdx.x;
  int b = bh >> 4, h = bh & 15;
  int tid = threadIdx.x, lane = tid & 63, w = tid >> 6;
  int g = lane >> 4, r = lane & 15;
  __shared__ ushort mb[512];
  for (int i = tid; i < 512; i += 256) mb[i] = mask01[b * SEQ + i];
  __syncthreads();
  s16x8 bkp[4][2], bqp[4][2];   // kpos / qpos B-fragments (t = nt*16+r)
  #pragma unroll
  for (int nt = 0; nt < 4; ++nt)
    #pragma unroll
    for (int kk = 0; kk < 2; ++kk) {
      size_t rowp = (size_t)(NROWS + nt * 16 + r);
      int colq = h * 64 + kk * 32 + g * 8;
      bqp[nt][kk] = *(const s16x8*)(qkv + rowp * NQKV + colq);
      bkp[nt][kk] = *(const s16x8*)(qkv + rowp * NQKV + 1024 + colq);
    }
  for (int cc = 0; cc < 8; ++cc) {
    int rowbase = cc * 64 + w * 16;
    s16x8 aq[2], ak[2];
    #pragma unroll
    for (int kk = 0; kk < 2; ++kk) {
      size_t rowq = (size_t)((rowbase + r) * 16 + b);
      int colq = h * 64 + kk * 32 + g * 8;
      aq[kk] = *(const s16x8*)(qkv + rowq * NQKV + colq);
      ak[kk] = *(const s16x8*)(qkv + rowq * NQKV + 1024 + colq);
    }
    f32x4 accq[4] = {}, acck[4] = {};
    #pragma unroll
    for (int kk = 0; kk < 2; ++kk)
      #pragma unroll
      for (int nt = 0; nt < 4; ++nt) {
        accq[nt] = __builtin_amdgcn_mfma_f32_16x16x32_bf16(aq[kk], bkp[nt][kk], accq[nt], 0, 0, 0);
        acck[nt] = __builtin_amdgcn_mfma_f32_16x16x32_bf16(ak[kk], bqp[nt][kk], acck[nt], 0, 0, 0);
      }
    #pragma unroll
    for (int nt = 0; nt < 4; ++nt)
      #pragma unroll
      for (int i = 0; i < 4; ++i) {
        int q = rowbase + g * 4 + i;
        int t = nt * 16 + r;
        float biasv = mb[q] ? -1e9f : 0.0f;          // key-mask baked into pk rows
        qp[(size_t)bh * SEQ * 64 + q * 64 + t] = f2bf(accq[nt][i] * SCALE2);
        pk[(size_t)bh * SEQ * 64 + q * 64 + t] = f2bf(acck[nt][i] * SCALE2 + biasv);
      }
  }
}

// ---------------- V transpose + K repack (K pre-scaled, base-2): vt[b,h,d,l], kc[b,h,l,d]
__global__ __launch_bounds__(256) void k_vt(const ushort* qkv, ushort* vt, ushort* kc) {
  int bid = blockIdx.x;
  int bh = bid >> 3, lt = bid & 7;
  int b = bh >> 4, h = bh & 15;
  __shared__ ushort tile[64][72];
  int tid = threadIdx.x;
  #pragma unroll
  for (int c = 0; c < 2; ++c) {
    int e = (c * 256 + tid) * 8;
    int l = e >> 6, d0 = e & 63;
    size_t row = (size_t)((lt * 64 + l) * 16 + b);
    s16x8 kv = *(const s16x8*)(qkv + row * NQKV + 1024 + h * 64 + d0);
    #pragma unroll
    for (int j = 0; j < 8; ++j) kv[j] = (short)f2bf(bf2f((ushort)kv[j]) * SCALE2);
    *(s16x8*)(kc + ((size_t)bh * SEQ + lt * 64 + l) * 64 + d0) = kv;   // scaled K rows
    *(s16x8*)&tile[l][d0] = *(const s16x8*)(qkv + row * NQKV + 2048 + h * 64 + d0);
  }
  __syncthreads();
  #pragma unroll
  for (int c = 0; c < 2; ++c) {
    int e = (c * 256 + tid) * 8;
    int d = e >> 6, l0 = e & 63;
    ushort tmp[8];
    #pragma unroll
    for (int j = 0; j < 8; ++j) tmp[j] = tile[l0 + j][d];
    *(s16x8*)(vt + (size_t)(bh * 64 + d) * SEQ + lt * 64 + l0) = *(s16x8*)tmp;
  }
}

// ---------------- fused attention: BARRIER-FREE main loop --------------------------------
__global__ __launch_bounds__(512) void k_attn(const ushort* qkv, const ushort* qp_all, const ushort* pk_all,
                                              const ushort* kc, const ushort* vt,
                                              const int* idx_tab, ushort* ctx) {
  int bid = blockIdx.x;
  int slot = bid >> 3;
  int bh = (bid & 7) * 32 + (slot >> 1);   // both q-halves of a bh on one XCD
  int qh = slot & 1;                       // which 256-row q half
  int b = bh >> 4, h = bh & 15;
  int tid = threadIdx.x, lane = tid & 63, w = tid >> 6;
  int g = lane >> 4, r = lane & 15;

  __shared__ ushort pk_f[512][68];   // 69,632 B  full-k pk table
  __shared__ ushort qp_s[256][68];   // 34,816 B  this half's qp rows
  __shared__ ushort p_s[8][16][68];  // 17,408 B  per-wave P staging
  __shared__ ushort idx_s[1024];     //  2,048 B  -> total 123,904 B

  const ushort* qpsrc = qp_all + (size_t)bh * SEQ * 64 + (size_t)qh * 256 * 64;
  const ushort* pksrc = pk_all + (size_t)bh * SEQ * 64;
  const char*   kcb   = (const char*)(kc + (size_t)bh * SEQ * 64);   // [l][d] 128B rows

  // ---- prologue: stage qp(256 rows), pk(512 rows), idx; load aq; ONE barrier ----
  #pragma unroll
  for (int c = 0; c < 4; ++c) {            // qp: 2048 chunks of 8 u16
    int chunk = c * 512 + tid;
    int row = chunk >> 3, col8 = (chunk & 7) * 8;
    s16x8 v = *(const s16x8*)(qpsrc + (size_t)row * 64 + col8);
    u16x4 lo = { (ushort)v[0], (ushort)v[1], (ushort)v[2], (ushort)v[3] };
    u16x4 hi = { (ushort)v[4], (ushort)v[5], (ushort)v[6], (ushort)v[7] };
    *(u16x4*)&qp_s[row][col8] = lo;
    *(u16x4*)&qp_s[row][col8 + 4] = hi;
  }
  #pragma unroll
  for (int c = 0; c < 8; ++c) {            // pk: 4096 chunks of 8 u16
    int chunk = c * 512 + tid;
    int row = chunk >> 3, col8 = (chunk & 7) * 8;
    s16x8 v = *(const s16x8*)(pksrc + (size_t)row * 64 + col8);
    u16x4 lo = { (ushort)v[0], (ushort)v[1], (ushort)v[2], (ushort)v[3] };
    u16x4 hi = { (ushort)v[4], (ushort)v[5], (ushort)v[6], (ushort)v[7] };
    *(u16x4*)&pk_f[row][col8] = lo;
    *(u16x4*)&pk_f[row][col8 + 4] = hi;
  }
  for (int i = tid; i < 1023; i += 512) idx_s[i] = (ushort)idx_tab[i];
  s16x8 aq[2][2];                          // [qs][kk] Q fragments for this wave's 2 subtiles
  #pragma unroll
  for (int qs = 0; qs < 2; ++qs)
    #pragma unroll
    for (int kk = 0; kk < 2; ++kk) {
      int qglob = qh * 256 + qs * 128 + w * 16 + r;
      aq[qs][kk] = *(const s16x8*)(qkv + ((size_t)qglob * 16 + b) * NQKV + h * 64 + kk * 32 + g * 8);
    }
  __syncthreads();   // the ONLY barrier

  float m_i[2] = { -3e38f, -3e38f }, l_i[2] = { 0.0f, 0.0f };
  f32x4 o_acc[2][4] = {};

  for (int kt = 0; kt < 8; ++kt) {
    // K and V fragments straight from global (L2-shared across the block's 8 waves)
    s16x8 kf[4][2], vf[2][4];
    #pragma unroll
    for (int nt = 0; nt < 4; ++nt)
      #pragma unroll
      for (int kk = 0; kk < 2; ++kk)
        kf[nt][kk] = *(const s16x8*)(kcb + (size_t)(kt * 64 + nt * 16 + r) * 128 + kk * 64 + g * 16);
    #pragma unroll
    for (int kk = 0; kk < 2; ++kk)
      #pragma unroll
      for (int nt = 0; nt < 4; ++nt)
        vf[kk][nt] = *(const s16x8*)(vt + (size_t)(bh * 64 + nt * 16 + r) * SEQ + kt * 64 + kk * 32 + g * 8);

    #pragma unroll
    for (int qs = 0; qs < 2; ++qs) {
      // ---- swapped QK^T: lane holds S^T for q = r, k = nt*16+g*4+i ----
      f32x4 s[4];
      #pragma unroll
      for (int nt = 0; nt < 4; ++nt) {
        f32x4 a = {};
        #pragma unroll
        for (int kk = 0; kk < 2; ++kk)
          a = __builtin_amdgcn_mfma_f32_16x16x32_bf16(kf[nt][kk], aq[qs][kk], a, 0, 0, 0);   // A=K, B=Q
        s[nt] = a;
      }

      // ---- gather: v = c2c + qp[q][t] + pk[k][t]  (base-2 pre-scaled, mask in pk) ----
      const ushort* qprow = &qp_s[qs * 128 + w * 16 + r][0];
      const int qg511 = qh * 256 + qs * 128 + w * 16 + r + 511;
      float m_loc = -3e38f;
      #pragma unroll
      for (int nt = 0; nt < 4; ++nt) {
        #pragma unroll
        for (int i = 0; i < 4; ++i) {
          int kg = kt * 64 + nt * 16 + g * 4 + i;
          int t = idx_s[qg511 - kg];
          float v = s[nt][i] + bf2f(qprow[t]) + bf2f(pk_f[kg][t]);
          s[nt][i] = v;
          m_loc = fmaxf(m_loc, v);
        }
      }

      // ---- row max across the 4 g-lanes holding q = r ----
      float mx = fmaxf(m_loc, __shfl_xor(m_loc, 16));
      mx = fmaxf(mx, __shfl_xor(mx, 32));

      // ---- T13 defer-rescale (base-2 threshold 8) ----
      if (__any(mx > m_i[qs] + 8.0f)) {
        float mnew = fmaxf(m_i[qs], mx);
        float rs = exp2f(m_i[qs] - mnew);
        m_i[qs] = mnew;
        l_i[qs] *= rs;
        float rsb[4];
        #pragma unroll
        for (int i = 0; i < 4; ++i) rsb[i] = __shfl(rs, g * 4 + i);   // rs for q = g*4+i
        #pragma unroll
        for (int nt = 0; nt < 4; ++nt)
          #pragma unroll
          for (int i = 0; i < 4; ++i) o_acc[qs][nt][i] *= rsb[i];
      }

      // ---- exp2 + P pack (b64 LDS writes), psum ----
      float psum = 0.0f;
      #pragma unroll
      for (int nt = 0; nt < 4; ++nt) {
        u16x4 pk4;
        #pragma unroll
        for (int i = 0; i < 4; ++i) {
          float pe = exp2f(s[nt][i] - m_i[qs]);   // masked: huge negative -> exact 0
          psum += pe;
          pk4[i] = f2bf(pe);
        }
        *(u16x4*)&p_s[w][r][nt * 16 + g * 4] = pk4;
      }
      psum += __shfl_xor(psum, 16);
      psum += __shfl_xor(psum, 32);
      l_i[qs] += psum;

      // ---- PV (per-wave p_s roundtrip, ordered by lgkmcnt within the wave) ----
      #pragma unroll
      for (int kk = 0; kk < 2; ++kk) {
        u16x4 lo = *(const u16x4*)&p_s[w][r][kk * 32 + g * 8];
        u16x4 hi = *(const u16x4*)&p_s[w][r][kk * 32 + g * 8 + 4];
        s16x8 pa = { (short)lo[0], (short)lo[1], (short)lo[2], (short)lo[3],
                     (short)hi[0], (short)hi[1], (short)hi[2], (short)hi[3] };
        #pragma unroll
        for (int nt = 0; nt < 4; ++nt)
          o_acc[qs][nt] = __builtin_amdgcn_mfma_f32_16x16x32_bf16(pa, vf[kk][nt], o_acc[qs][nt], 0, 0, 0);
      }
    }
  }

  #pragma unroll
  for (int qs = 0; qs < 2; ++qs) {
    float lb[4];
    #pragma unroll
    for (int i = 0; i < 4; ++i) lb[i] = __shfl(l_i[qs], g * 4 + i);   // l for q = g*4+i
    #pragma unroll
    for (int i = 0; i < 4; ++i) {
      float inv = lb[i] > 0.0f ? 1.0f / lb[i] : 0.0f;
      int lq = qh * 256 + qs * 128 + w * 16 + g * 4 + i;
      size_t rowc = (size_t)(lq * 16 + b);
      #pragma unroll
      for (int nt = 0; nt < 4; ++nt)
        ctx[rowc * HID + h * 64 + nt * 16 + r] = f2bf(o_acc[qs][nt][i] * inv);
    }
  }
}

// ---------------- LN2 (affine), two bf16 partials in -> f32 out --------------------------
__global__ __launch_bounds__(256) void k_ln2(const ushort* t0, const ushort* t1,
                                             const float* gamma, const float* beta, float* out) {
  int row = blockIdx.x, tid = threadIdx.x;
  __shared__ float red[8];
  u16x4 xa = *(const u16x4*)(t0 + (size_t)row * HID + tid * 4);
  u16x4 xb = *(const u16x4*)(t1 + (size_t)row * HID + tid * 4);
  float x[4];
  #pragma unroll
  for (int j = 0; j < 4; ++j) x[j] = bf2f(xa[j]) + bf2f(xb[j]);
  float s = x[0] + x[1] + x[2] + x[3];
  #pragma unroll
  for (int m = 1; m < 64; m <<= 1) s += __shfl_xor(s, m);
  if ((tid & 63) == 0) red[tid >> 6] = s;
  __syncthreads();
  float mean = (red[0] + red[1] + red[2] + red[3]) * (1.0f / HID);
  float d[4]; float sq = 0.0f;
  #pragma unroll
  for (int j = 0; j < 4; ++j) { d[j] = x[j] - mean; sq += d[j] * d[j]; }
  #pragma unroll
  for (int m = 1; m < 64; m <<= 1) sq += __shfl_xor(sq, m);
  __syncthreads();
  if ((tid & 63) == 0) red[4 + (tid >> 6)] = sq;
  __syncthreads();
  float var = (red[4] + red[5] + red[6] + red[7]) * (1.0f / HID);
  float rs = rsqrtf(var + LNEPS);
  f32x4 o;
  #pragma unroll
  for (int j = 0; j < 4; ++j) o[j] = d[j] * rs * gamma[tid * 4 + j] + beta[tid * 4 + j];
  *(f32x4*)(out + (size_t)row * HID + tid * 4) = o;
}

// ---------------- launch -----------------------------------------------------------------
extern "C" void kernel_launch(void* const* d_in, const int* in_sizes, int n_in,
                              void* d_out, int out_size, void* d_ws, size_t ws_size,
                              hipStream_t stream) {
  (void)in_sizes; (void)n_in; (void)out_size; (void)ws_size;
  const float* hid  = (const float*)d_in[0];
  const void*  mask = d_in[1];
  const float* rel  = (const float*)d_in[2];
  const float* wqk  = (const float*)d_in[3];
  const float* bqk  = (const float*)d_in[4];
  const float* wv   = (const float*)d_in[5];
  const float* bv   = (const float*)d_in[6];
  const float* wo   = (const float*)d_in[7];
  const float* bo   = (const float*)d_in[8];
  const float* ln_g = (const float*)d_in[9];
  const float* ln_b = (const float*)d_in[10];

  char* ws = (char*)d_ws;
  ushort* wcat     = (ushort*)(ws);                 //  6,291,456
  ushort* wo_b     = (ushort*)(ws + 6291456);       //  2,097,152
  float*  bcat     = (float*) (ws + 8388608);       //     12,288
  ushort* mask01   = (ushort*)(ws + 8400896);       //     16,384 (region 32,768)
  int*    idx_tab  = (int*)   (ws + 8433664);       //      4,096
  ushort* h_ext    = (ushort*)(ws + 8437760);       // 17,039,360  (reused as ctx)
  ushort* qkv      = (ushort*)(ws + 25477120);      // 51,118,080
  ushort* qp_b     = (ushort*)(ws + 76595200);      // 16,777,216 (bf16, base-2 pre-scaled)
  ushort* pk_b     = (ushort*)(ws + 93372416);      // 16,777,216 (bf16, pre-scaled + mask)
  ushort* vt       = (ushort*)(ws + 110149632);     // 16,777,216
  char*   tmpr     = (ws + 126926848);              // 33,554,432 region
  ushort* ctx = h_ext;
  ushort* kc   = (ushort*)tmpr;                     // dead once k_attn finishes
  ushort* tmp0 = (ushort*)tmpr;                     // split-K partial 0 (16,777,216)
  ushort* tmp1 = (ushort*)(tmpr + 16777216);        // split-K partial 1 (16,777,216)

  k_prep<<<1, 256, 0, stream>>>(mask, bqk, bv, mask01, idx_tab, bcat);
  k_convert<<<4096, 256, 0, stream>>>(wqk, wv, wo, wcat, wo_b);
  k_ln1<<<MEXT, 256, 0, stream>>>(hid, rel, h_ext);
  k_gemm256<<<33 * (NQKV / 128), 512, 0, stream>>>(h_ext, wcat, bcat, qkv, MEXT, NQKV, 1024);
  k_pos<<<256, 256, 0, stream>>>(qkv, mask01, qp_b, pk_b);
  k_vt<<<2048, 256, 0, stream>>>(qkv, vt, kc);
  k_attn<<<512, 512, 0, stream>>>(qkv, qp_b, pk_b, kc, vt, idx_tab, ctx);
  k_gemm_sk<<<1024, 256, 0, stream>>>(ctx, wo_b, bo, tmp0, tmp1);
  k_ln2<<<NROWS, 256, 0, stream>>>(tmp0, tmp1, ln_g, ln_b, (float*)d_out);
}